// Round 13
// baseline (491.331 us; speedup 1.0000x reference)
//
#include <hip/hip_runtime.h>

typedef unsigned short u16;
typedef __attribute__((ext_vector_type(8))) short short8;
typedef __attribute__((ext_vector_type(4))) float floatx4;

#define MFMA16(a, b, c) __builtin_amdgcn_mfma_f32_16x16x32_bf16((a), (b), (c), 0, 0, 0)

// B=4, C=128, I=64, N=4096. fp32 I/O; bf16 intermediates.
#define SZ_P ((size_t)4 * 64 * 4096)   // 1,048,576 el

__device__ __forceinline__ float bf2f(u16 u) {
    union { unsigned int i; float f; } v; v.i = ((unsigned int)u) << 16; return v.f;
}
__device__ __forceinline__ u16 f2bf(float f) {
    union { float f; unsigned int i; } v; v.f = f;
    unsigned int r = v.i + 0x7fffu + ((v.i >> 16) & 1u);
    return (u16)(r >> 16);
}
__device__ __forceinline__ unsigned int pk2(float a, float b) {
    union { float f; unsigned int u; } x, y; x.f = a; y.f = b;
    return (x.u >> 16) | (y.u & 0xffff0000u);
}

// software grid barrier: all 512 blocks are HW-co-resident (LDS 55.3KB ->
// exactly 2 blocks/CU x 256 CUs). Counters zeroed by hipMemsetAsync each call.
__device__ __forceinline__ void gbar(unsigned int* ctr, unsigned int target) {
    __syncthreads();
    __threadfence();                       // release: publish stores device-wide
    if (threadIdx.x == 0) {
        atomicAdd(ctr, 1u);
        while (atomicAdd(ctr, 0u) < target) __builtin_amdgcn_s_sleep(8);
    }
    __syncthreads();
    __threadfence();                       // acquire: invalidate stale caches
}

// ---------------------------------------------------------------------------
// Persistent mega-kernel: W (weights->bf16) | P (proj) | F (flash) | E (epi)
// grid = 512 x 256, 55.3 KB LDS -> 2 blocks/CU co-resident.
// ---------------------------------------------------------------------------
__global__ __launch_bounds__(256) void k_mega(
    const float* __restrict__ x, const float* __restrict__ mask,
    const float* __restrict__ wt_nl, const float* __restrict__ bt_nl,
    const float* __restrict__ wp_nl, const float* __restrict__ bp_nl,
    const float* __restrict__ wt_l,  const float* __restrict__ bt_l,
    const float* __restrict__ wp_l,  const float* __restrict__ bp_l,
    const float* __restrict__ wg_nl, const float* __restrict__ bg_nl,
    const float* __restrict__ wg_l,  const float* __restrict__ bg_l,
    const float* __restrict__ wW,  const float* __restrict__ bW,
    const float* __restrict__ gW,  const float* __restrict__ betaW,
    const float* __restrict__ wWl, const float* __restrict__ gWl,
    const float* __restrict__ betaWl,
    float* __restrict__ out,
    u16* __restrict__ wbf,
    u16* __restrict__ q0, u16* __restrict__ k0, u16* __restrict__ v0,
    u16* __restrict__ q1, u16* __restrict__ k1, u16* __restrict__ v1,
    u16* __restrict__ num, float* __restrict__ den,
    unsigned int* __restrict__ bar)
{
    __shared__ __align__(16) u16 smem[27648];   // 55,296 B
    const int flat = blockIdx.x;
    const int t = threadIdx.x, w = t >> 6, lane = t & 63;
    const int quad = lane >> 4, l15 = lane & 15;

    // ---------------- Phase W: weights fp32 -> bf16 --------------------------
    {
        const int idx = flat * 256 + t;
        if (idx < 61440) {
            float v;
            if (idx < 49152) {
                const int j = idx >> 13, off = idx & 8191;
                const float* s = (j == 0) ? wt_nl : (j == 1) ? wp_nl : (j == 2) ? wg_nl
                               : (j == 3) ? wt_l : (j == 4) ? wp_l : wg_l;
                v = s[off];
            } else if (idx < 53248) {
                v = wWl[idx - 49152];
            } else {
                v = wW[idx - 53248];
            }
            wbf[idx] = f2bf(v);
        }
    }
    gbar(bar, 512);

    // ---------------- Phase P: projections ----------------------------------
    // br = flat&1, b = (flat>>1)&3, n-tile = flat>>3 (64 tiles of 64)
    {
        u16* xt_s = smem;   // [n][c] bf16, 64 x 136
        const int br = flat & 1, b = (flat >> 1) & 3, n0 = (flat >> 3) * 64;
        const u16* wq = wbf + br * 24576;
        const u16* wk = wq + 8192;
        const u16* wv = wk + 8192;
        const float* bq = br ? bt_l : bt_nl;
        const float* bk = br ? bp_l : bp_nl;
        const float* bv = br ? bg_l : bg_nl;
        u16* q = br ? q1 : q0;  u16* k = br ? k1 : k0;  u16* v = br ? v1 : v0;
        const float* xb = x + ((size_t)b << 19);

        for (int idx = t; idx < 8192; idx += 256) {
            const int c = idx >> 6, n = idx & 63;
            xt_s[n * 136 + c] = f2bf(xb[((size_t)c << 12) + n0 + n]);
        }
        __syncthreads();

        short8 ax[4];
#pragma unroll
        for (int cc = 0; cc < 4; ++cc)
            ax[cc] = *(const short8*)&xt_s[(w * 16 + l15) * 136 + quad * 8 + cc * 32];

        float mv[4] = {1.f, 1.f, 1.f, 1.f};
        if (br) {
#pragma unroll
            for (int r = 0; r < 4; ++r)
                mv[r] = mask[((size_t)b << 12) + n0 + w * 16 + quad * 4 + r];
        }

#pragma unroll
        for (int qk = 0; qk < 2; ++qk) {
            const u16* wsel = qk ? wk : wq;
            const float* bb = qk ? bk : bq;
            u16* o = qk ? k : q;
#pragma unroll
            for (int ns = 0; ns < 4; ++ns) {
                floatx4 acc = {0.f, 0.f, 0.f, 0.f};
                const u16* wp = wsel + (ns * 16 + l15) * 128 + quad * 8;
#pragma unroll
                for (int cc = 0; cc < 4; ++cc)
                    acc = MFMA16(ax[cc], *(const short8*)(wp + cc * 32), acc);
                const float bias_i = bb[ns * 16 + l15];
#pragma unroll
                for (int r = 0; r < 4; ++r) {
                    const float val = (acc[r] + bias_i) * mv[r];
                    o[((size_t)b << 18) + (size_t)(n0 + w * 16 + quad * 4 + r) * 64
                      + ns * 16 + l15] = f2bf(val);
                }
            }
        }

        short8 aw[4];
#pragma unroll
        for (int cc = 0; cc < 4; ++cc)
            aw[cc] = *(const short8*)(wv + (w * 16 + l15) * 128 + quad * 8 + cc * 32);
        float bvr[4];
#pragma unroll
        for (int r = 0; r < 4; ++r) bvr[r] = bv[w * 16 + quad * 4 + r];
#pragma unroll
        for (int ns = 0; ns < 4; ++ns) {
            floatx4 acc = {0.f, 0.f, 0.f, 0.f};
#pragma unroll
            for (int cc = 0; cc < 4; ++cc)
                acc = MFMA16(aw[cc],
                    *(const short8*)&xt_s[(ns * 16 + l15) * 136 + quad * 8 + cc * 32], acc);
#pragma unroll
            for (int r = 0; r < 4; ++r) {
                v[((size_t)b << 18) + ((size_t)(w * 16 + quad * 4 + r) << 12)
                  + n0 + ns * 16 + l15] = f2bf(acc[r] + bvr[r]);
            }
        }
    }
    gbar(bar + 4, 512);

    // ---------------- Phase F: attention (split-K x2) ------------------------
    {
        u16* kt_sb = smem;              // 2 x 4608
        u16* vt_sb = smem + 9216;       // 2 x 4608
        u16* p_s   = smem + 18432;      // 4 x 32 x 72

        const int g = flat & 15, tile = flat >> 4;
        const int b = g >> 2, z = g & 3;
        const int br = z >> 1, sp = z & 1;
        const int qb = tile * 128;
        const size_t base = ((size_t)b << 18);
        const u16* Q = (br ? q1 : q0) + base;
        const u16* K = (br ? k1 : k0) + base;
        const u16* V = (br ? v1 : v0) + base;
        u16* numo = num + (size_t)z * SZ_P + base;
        float* deno = den + z * 16384 + b * 4096;

        const int pw = w * 32 * 72;
        const int r0 = t >> 3, r1 = (t + 256) >> 3, cg8 = (t & 7) * 8;
        const u16* Kp0 = K + (size_t)r0 * 64 + cg8;
        const u16* Kp1 = K + (size_t)r1 * 64 + cg8;
        const u16* Vp0 = V + ((size_t)r0 << 12) + cg8;
        const u16* Vp1 = V + ((size_t)r1 << 12) + cg8;
        const int lk0 = r0 * 72 + cg8, lk1 = r1 * 72 + cg8;

        short8 aq[2][2];
#pragma unroll
        for (int t2 = 0; t2 < 2; ++t2)
#pragma unroll
            for (int s = 0; s < 2; ++s)
                aq[t2][s] = *(const short8*)(Q + (size_t)(qb + w * 32 + t2 * 16 + l15) * 64
                                             + s * 32 + quad * 8);

        const short8 ones8 = {0x3F80, 0x3F80, 0x3F80, 0x3F80,
                              0x3F80, 0x3F80, 0x3F80, 0x3F80};
        floatx4 oacc[4][2];
#pragma unroll
        for (int it = 0; it < 4; ++it)
#pragma unroll
            for (int t2 = 0; t2 < 2; ++t2) oacc[it][t2] = (floatx4){0.f, 0.f, 0.f, 0.f};
        floatx4 lacc[2] = {{0.f, 0.f, 0.f, 0.f}, {0.f, 0.f, 0.f, 0.f}};

        const int roff = tile & 31;
        const int m_beg = sp * 2048;

        {
            const int m0 = m_beg + (roff << 6);
            *(short8*)&kt_sb[lk0] = *(const short8*)(Kp0 + (size_t)m0 * 64);
            *(short8*)&kt_sb[lk1] = *(const short8*)(Kp1 + (size_t)m0 * 64);
            *(short8*)&vt_sb[lk0] = *(const short8*)(Vp0 + m0);
            *(short8*)&vt_sb[lk1] = *(const short8*)(Vp1 + m0);
        }

        for (int j = 0; j < 32; ++j) {
            const int cur = j & 1;
            u16* ktc = kt_sb + cur * 4608;
            u16* vtc = vt_sb + cur * 4608;
            u16* ktn = kt_sb + (cur ^ 1) * 4608;
            u16* vtn = vt_sb + (cur ^ 1) * 4608;
            const int mn = m_beg + (((roff + j + 1) & 31) << 6);
            short8 pk0v = *(const short8*)(Kp0 + (size_t)mn * 64);
            short8 pk1v = *(const short8*)(Kp1 + (size_t)mn * 64);
            short8 pv0v = *(const short8*)(Vp0 + mn);
            short8 pv1v = *(const short8*)(Vp1 + mn);
            __syncthreads();

#pragma unroll
            for (int mt = 0; mt < 4; ++mt) {
                const u16* kp = &ktc[(mt * 16 + l15) * 72 + quad * 8];
                const short8 ka0 = *(const short8*)kp;
                const short8 ka1 = *(const short8*)(kp + 32);
#pragma unroll
                for (int t2 = 0; t2 < 2; ++t2) {
                    floatx4 acc = {0.f, 0.f, 0.f, 0.f};
                    acc = MFMA16(ka0, aq[t2][0], acc);
                    acc = MFMA16(ka1, aq[t2][1], acc);
                    const float e0 = __expf(acc[0]), e1 = __expf(acc[1]);
                    const float e2 = __expf(acc[2]), e3 = __expf(acc[3]);
                    *(uint2*)&p_s[pw + (t2 * 16 + l15) * 72 + mt * 16 + quad * 4] =
                        make_uint2(pk2(e0, e1), pk2(e2, e3));
                }
            }

            short8 pb2[2][2];
#pragma unroll
            for (int t2 = 0; t2 < 2; ++t2)
#pragma unroll
                for (int s = 0; s < 2; ++s)
                    pb2[t2][s] = *(const short8*)&p_s[pw + (t2 * 16 + l15) * 72 + s * 32 + quad * 8];
#pragma unroll
            for (int it = 0; it < 4; ++it) {
                const u16* vp = &vtc[(it * 16 + l15) * 72 + quad * 8];
                const short8 va0 = *(const short8*)vp;
                const short8 va1 = *(const short8*)(vp + 32);
#pragma unroll
                for (int t2 = 0; t2 < 2; ++t2) {
                    oacc[it][t2] = MFMA16(va0, pb2[t2][0], oacc[it][t2]);
                    oacc[it][t2] = MFMA16(va1, pb2[t2][1], oacc[it][t2]);
                }
            }
#pragma unroll
            for (int t2 = 0; t2 < 2; ++t2) {
                lacc[t2] = MFMA16(ones8, pb2[t2][0], lacc[t2]);
                lacc[t2] = MFMA16(ones8, pb2[t2][1], lacc[t2]);
            }

            *(short8*)&ktn[lk0] = pk0v;
            *(short8*)&ktn[lk1] = pk1v;
            *(short8*)&vtn[lk0] = pv0v;
            *(short8*)&vtn[lk1] = pv1v;
        }

        if (quad == 0) {
#pragma unroll
            for (int t2 = 0; t2 < 2; ++t2)
                deno[qb + w * 32 + t2 * 16 + l15] = lacc[t2][0];
        }

#pragma unroll
        for (int it = 0; it < 4; ++it)
#pragma unroll
            for (int t2 = 0; t2 < 2; ++t2) {
                *(uint2*)&p_s[pw + (t2 * 16 + l15) * 72 + it * 16 + quad * 4] =
                    make_uint2(pk2(oacc[it][t2][0], oacc[it][t2][1]),
                               pk2(oacc[it][t2][2], oacc[it][t2][3]));
            }
        __syncthreads();
#pragma unroll
        for (int ch = t; ch < 1024; ch += 256) {
            const int row = ch >> 3, cg = ch & 7;
            *(short8*)(numo + (size_t)(qb + row) * 64 + cg * 8) =
                *(const short8*)&p_s[(row >> 5) * 2304 + (row & 31) * 72 + cg * 8];
        }
    }
    gbar(bar + 8, 512);

    // ---------------- Phase E: epilogue + split-K reduce ---------------------
    // b = flat&3, n-tile(32) = flat>>2 (128 tiles); full c-range.
    {
        u16* yl_s  = smem;          // 32 x 72
        u16* ynl_s = smem + 2304;
        u16* yy_s  = smem + 4608;
        const int b = flat & 3, n0 = (flat >> 2) * 32;
        const size_t ybase = ((size_t)b << 18) + (size_t)n0 * 64;

        {
            const int row = t >> 3, cg = t & 7;
            const float dn = den[b * 4096 + n0 + row] + den[16384 + b * 4096 + n0 + row];
            const float dl = den[32768 + b * 4096 + n0 + row] + den[49152 + b * 4096 + n0 + row];
            const float inl = 1.0f / dn, ilo = 1.0f / dl;
            const short8 a0 = *(const short8*)(num + ybase + row * 64 + cg * 8);
            const short8 a1 = *(const short8*)(num + SZ_P + ybase + row * 64 + cg * 8);
            const short8 c0 = *(const short8*)(num + 2 * SZ_P + ybase + row * 64 + cg * 8);
            const short8 c1 = *(const short8*)(num + 3 * SZ_P + ybase + row * 64 + cg * 8);
            short8 ynl8, yl8;
#pragma unroll
            for (int j = 0; j < 8; ++j) {
                ynl8[j] = (short)f2bf((bf2f((u16)a0[j]) + bf2f((u16)a1[j])) * inl);
                yl8[j]  = (short)f2bf((bf2f((u16)c0[j]) + bf2f((u16)c1[j])) * ilo);
            }
            *(short8*)&ynl_s[row * 72 + cg * 8] = ynl8;
            *(short8*)&yl_s[row * 72 + cg * 8] = yl8;
        }
        __syncthreads();
        const float rsq = rsqrtf(1.0f + 1e-5f);
        const u16* wblW = wbf + 49152;
        const u16* wbW  = wbf + 53248;

        // E1: yy = bn(relu(wWl . y_l)) + y_nl
        {
            const short8 a0 = *(const short8*)(wblW + (w * 16 + l15) * 64 + quad * 8);
            const short8 a1 = *(const short8*)(wblW + (w * 16 + l15) * 64 + 32 + quad * 8);
            float sc[4], bt[4];
#pragma unroll
            for (int r = 0; r < 4; ++r) {
                const int io = w * 16 + quad * 4 + r;
                sc[r] = gWl[io] * rsq;
                bt[r] = betaWl[io];
            }
#pragma unroll
            for (int ns = 0; ns < 2; ++ns) {
                floatx4 acc = {0.f, 0.f, 0.f, 0.f};
                const u16* bp_ = &yl_s[(ns * 16 + l15) * 72 + quad * 8];
                acc = MFMA16(a0, *(const short8*)bp_, acc);
                acc = MFMA16(a1, *(const short8*)(bp_ + 32), acc);
#pragma unroll
                for (int r = 0; r < 4; ++r) {
                    const int io = w * 16 + quad * 4 + r;
                    float val = fmaxf(acc[r], 0.f) * sc[r] + bt[r];
                    val += bf2f(ynl_s[(ns * 16 + l15) * 72 + io]);
                    yy_s[(ns * 16 + l15) * 72 + io] = f2bf(val);
                }
            }
        }
        __syncthreads();

        // E2: out = bn(relu(wW . yy + bW)) + x
#pragma unroll
        for (int rb = 0; rb < 2; ++rb) {
            const int c0 = rb * 64 + w * 16;
            const short8 a0 = *(const short8*)(wbW + (c0 + l15) * 64 + quad * 8);
            const short8 a1 = *(const short8*)(wbW + (c0 + l15) * 64 + 32 + quad * 8);
            float bs[4], sc[4], bt[4];
#pragma unroll
            for (int r = 0; r < 4; ++r) {
                const int c = c0 + quad * 4 + r;
                bs[r] = bW[c];
                sc[r] = gW[c] * rsq;
                bt[r] = betaW[c];
            }
#pragma unroll
            for (int ns = 0; ns < 2; ++ns) {
                floatx4 acc = {0.f, 0.f, 0.f, 0.f};
                const u16* bp_ = &yy_s[(ns * 16 + l15) * 72 + quad * 8];
                acc = MFMA16(a0, *(const short8*)bp_, acc);
                acc = MFMA16(a1, *(const short8*)(bp_ + 32), acc);
#pragma unroll
                for (int r = 0; r < 4; ++r) {
                    const int c = c0 + quad * 4 + r;
                    float val = fmaxf(acc[r] + bs[r], 0.f) * sc[r] + bt[r];
                    const size_t xi = ((size_t)b << 19) + ((size_t)c << 12)
                                    + n0 + ns * 16 + l15;
                    out[xi] = val + x[xi];
                }
            }
        }
    }
}

// ---------------------------------------------------------------------------
extern "C" void kernel_launch(void* const* d_in, const int* in_sizes, int n_in,
                              void* d_out, int out_size, void* d_ws, size_t ws_size,
                              hipStream_t stream) {
    const float* x      = (const float*)d_in[0];
    const float* mask   = (const float*)d_in[1];
    const float* wt_nl  = (const float*)d_in[2];  const float* bt_nl = (const float*)d_in[3];
    const float* wp_nl  = (const float*)d_in[4];  const float* bp_nl = (const float*)d_in[5];
    const float* wt_l   = (const float*)d_in[6];  const float* bt_l  = (const float*)d_in[7];
    const float* wp_l   = (const float*)d_in[8];  const float* bp_l  = (const float*)d_in[9];
    const float* wg_nl  = (const float*)d_in[10]; const float* bg_nl = (const float*)d_in[11];
    const float* wg_l   = (const float*)d_in[12]; const float* bg_l  = (const float*)d_in[13];
    const float* wW     = (const float*)d_in[14]; const float* bW    = (const float*)d_in[15];
    const float* gW     = (const float*)d_in[16]; const float* betaW = (const float*)d_in[17];
    const float* wWl    = (const float*)d_in[18]; const float* gWl   = (const float*)d_in[19];
    const float* betaWl = (const float*)d_in[20];
    float* out = (float*)d_out;

    // ws: wbf 120KB + 6 qkv (12MB) + num 4x2MB + den 256KB + barriers
    u16* ws  = (u16*)d_ws;
    u16* wbf = ws;
    u16* q0  = wbf + 61440;
    u16* k0  = q0 + SZ_P;
    u16* v0  = k0 + SZ_P;
    u16* q1  = v0 + SZ_P;
    u16* k1  = q1 + SZ_P;
    u16* v1  = k1 + SZ_P;
    u16* num = v1 + SZ_P;
    float* den = (float*)(num + 4 * SZ_P);
    unsigned int* bar = (unsigned int*)(den + 4 * 16384);  // 3 counters, 16B apart

    hipMemsetAsync((void*)bar, 0, 48, stream);
    k_mega<<<dim3(512), dim3(256), 0, stream>>>(
        x, mask, wt_nl, bt_nl, wp_nl, bp_nl, wt_l, bt_l, wp_l, bp_l,
        wg_nl, bg_nl, wg_l, bg_l, wW, bW, gW, betaW, wWl, gWl, betaWl,
        out, wbf, q0, k0, v0, q1, k1, v1, num, den, bar);
}

// Round 14
// 189.677 us; speedup vs baseline: 2.5904x; 2.5904x over previous
//
#include <hip/hip_runtime.h>

typedef unsigned short u16;
typedef __attribute__((ext_vector_type(8))) short short8;
typedef __attribute__((ext_vector_type(4))) float floatx4;

#define MFMA16(a, b, c) __builtin_amdgcn_mfma_f32_16x16x32_bf16((a), (b), (c), 0, 0, 0)

// B=4, C=128, I=64, N=4096. fp32 I/O; bf16 intermediates.
#define SZ_P ((size_t)4 * 64 * 4096)   // 1,048,576 el

__device__ __forceinline__ float bf2f(u16 u) {
    union { unsigned int i; float f; } v; v.i = ((unsigned int)u) << 16; return v.f;
}
__device__ __forceinline__ u16 f2bf(float f) {
    union { float f; unsigned int i; } v; v.f = f;
    unsigned int r = v.i + 0x7fffu + ((v.i >> 16) & 1u);
    return (u16)(r >> 16);
}
__device__ __forceinline__ short8 pack8(const float* __restrict__ p) {
    short8 r;
#pragma unroll
    for (int j = 0; j < 8; ++j) r[j] = (short)f2bf(p[j]);
    return r;
}
// truncation pack: 2 fp32 -> packed bf16x2 (bias cancels in softmax ratio)
__device__ __forceinline__ unsigned int pk2(float a, float b) {
    union { float f; unsigned int u; } x, y; x.f = a; y.f = b;
    return (x.u >> 16) | (y.u & 0xffff0000u);
}

// ---------------------------------------------------------------------------
// K1: both branches' projections (z = branch), in-LDS x transpose, fp32
// weights converted at fragment build (pack8). q,k bf16 [B,N,I]; v bf16 [B,I,N].
// ---------------------------------------------------------------------------
__global__ __launch_bounds__(256) void k_proj(
    const float* __restrict__ x, const float* __restrict__ mask,
    const float* __restrict__ wq0, const float* __restrict__ bq0,
    const float* __restrict__ wk0, const float* __restrict__ bk0,
    const float* __restrict__ wv0, const float* __restrict__ bv0,
    const float* __restrict__ wq1, const float* __restrict__ bq1,
    const float* __restrict__ wk1, const float* __restrict__ bk1,
    const float* __restrict__ wv1, const float* __restrict__ bv1,
    u16* __restrict__ q0, u16* __restrict__ k0, u16* __restrict__ v0,
    u16* __restrict__ q1, u16* __restrict__ k1, u16* __restrict__ v1)
{
    __shared__ __align__(16) u16 xt_s[64 * 136];  // [n][c] bf16, pad 128->136
    const int n0 = blockIdx.x * 64, b = blockIdx.y, br = blockIdx.z;
    const float* wq = br ? wq1 : wq0;  const float* bq = br ? bq1 : bq0;
    const float* wk = br ? wk1 : wk0;  const float* bk = br ? bk1 : bk0;
    const float* wv = br ? wv1 : wv0;  const float* bv = br ? bv1 : bv0;
    u16* q = br ? q1 : q0;  u16* k = br ? k1 : k0;  u16* v = br ? v1 : v0;

    const int t = threadIdx.x, w = t >> 6, lane = t & 63;
    const int quad = lane >> 4, l15 = lane & 15;
    const float* xb = x + ((size_t)b << 19);

    for (int idx = t; idx < 8192; idx += 256) {
        const int c = idx >> 6, n = idx & 63;
        xt_s[n * 136 + c] = f2bf(xb[((size_t)c << 12) + n0 + n]);
    }
    __syncthreads();

    short8 ax[4];
#pragma unroll
    for (int cc = 0; cc < 4; ++cc)
        ax[cc] = *(const short8*)&xt_s[(w * 16 + l15) * 136 + quad * 8 + cc * 32];

    float mv[4] = {1.f, 1.f, 1.f, 1.f};
    if (br) {
#pragma unroll
        for (int r = 0; r < 4; ++r)
            mv[r] = mask[((size_t)b << 12) + n0 + w * 16 + quad * 4 + r];
    }

    // Q and K: D[n][i]
#pragma unroll
    for (int qk = 0; qk < 2; ++qk) {
        const float* wsel = qk ? wk : wq;
        const float* bb = qk ? bk : bq;
        u16* o = qk ? k : q;
#pragma unroll
        for (int ns = 0; ns < 4; ++ns) {
            floatx4 acc = {0.f, 0.f, 0.f, 0.f};
            const float* wp = wsel + (ns * 16 + l15) * 128 + quad * 8;
#pragma unroll
            for (int cc = 0; cc < 4; ++cc)
                acc = MFMA16(ax[cc], pack8(wp + cc * 32), acc);
            const float bias_i = bb[ns * 16 + l15];
#pragma unroll
            for (int r = 0; r < 4; ++r) {
                const float val = (acc[r] + bias_i) * mv[r];
                o[((size_t)b << 18) + (size_t)(n0 + w * 16 + quad * 4 + r) * 64
                  + ns * 16 + l15] = f2bf(val);
            }
        }
    }

    // V: D[i][n]
    short8 aw[4];
#pragma unroll
    for (int cc = 0; cc < 4; ++cc)
        aw[cc] = pack8(wv + (w * 16 + l15) * 128 + quad * 8 + cc * 32);
    float bvr[4];
#pragma unroll
    for (int r = 0; r < 4; ++r) bvr[r] = bv[w * 16 + quad * 4 + r];
#pragma unroll
    for (int ns = 0; ns < 4; ++ns) {
        floatx4 acc = {0.f, 0.f, 0.f, 0.f};
#pragma unroll
        for (int cc = 0; cc < 4; ++cc)
            acc = MFMA16(aw[cc],
                *(const short8*)&xt_s[(ns * 16 + l15) * 136 + quad * 8 + cc * 32], acc);
#pragma unroll
        for (int r = 0; r < 4; ++r) {
            v[((size_t)b << 18) + ((size_t)(w * 16 + quad * 4 + r) << 12)
              + n0 + ns * 16 + l15] = f2bf(acc[r] + bvr[r]);
        }
    }
}

// ---------------------------------------------------------------------------
// K2: attention, split-K x2 (r10 body verbatim — best measured: 63.5 us).
// 1-D grid, (b,z) in FAST 4 bits (XCD locality). Double-buffered staging,
// per-block m-rotation. Truncation-pack bf16 for P and O^T.
// ---------------------------------------------------------------------------
__global__ __launch_bounds__(256) void k_flash(
    const u16* __restrict__ Q0, const u16* __restrict__ K0,
    const u16* __restrict__ V0,
    const u16* __restrict__ Q1, const u16* __restrict__ K1,
    const u16* __restrict__ V1,
    u16* __restrict__ num, float* __restrict__ den)
{
    __shared__ __align__(16) u16 kt_s[2][64 * 72];
    __shared__ __align__(16) u16 vt_s[2][64 * 72];
    __shared__ __align__(16) u16 p_s[4 * 32 * 72];

    const int flat = blockIdx.x;
    const int g = flat & 15, tile = flat >> 4;
    const int b = g >> 2, z = g & 3;
    const int br = z >> 1, sp = z & 1;
    const int qb = tile * 128;
    const size_t base = ((size_t)b << 18);
    const u16* Q = (br ? Q1 : Q0) + base;
    const u16* K = (br ? K1 : K0) + base;
    const u16* V = (br ? V1 : V0) + base;
    u16* numo = num + (size_t)z * SZ_P + base;
    float* deno = den + z * 16384 + b * 4096;

    const int t = threadIdx.x, w = t >> 6, lane = t & 63;
    const int quad = lane >> 4, l15 = lane & 15;
    const int pw = w * 32 * 72;

    const int r0 = t >> 3, r1 = (t + 256) >> 3, cg8 = (t & 7) * 8;
    const u16* Kp0 = K + (size_t)r0 * 64 + cg8;
    const u16* Kp1 = K + (size_t)r1 * 64 + cg8;
    const u16* Vp0 = V + ((size_t)r0 << 12) + cg8;
    const u16* Vp1 = V + ((size_t)r1 << 12) + cg8;
    const int lk0 = r0 * 72 + cg8, lk1 = r1 * 72 + cg8;

    short8 aq[2][2];
#pragma unroll
    for (int t2 = 0; t2 < 2; ++t2)
#pragma unroll
        for (int s = 0; s < 2; ++s)
            aq[t2][s] = *(const short8*)(Q + (size_t)(qb + w * 32 + t2 * 16 + l15) * 64
                                         + s * 32 + quad * 8);

    floatx4 oacc[4][2];
#pragma unroll
    for (int it = 0; it < 4; ++it)
#pragma unroll
        for (int t2 = 0; t2 < 2; ++t2) oacc[it][t2] = (floatx4){0.f, 0.f, 0.f, 0.f};
    float dacc[2] = {0.f, 0.f};

    const int roff = tile & 31;
    const int m_beg = sp * 2048;

    {
        const int m0 = m_beg + (roff << 6);
        *(short8*)&kt_s[0][lk0] = *(const short8*)(Kp0 + (size_t)m0 * 64);
        *(short8*)&kt_s[0][lk1] = *(const short8*)(Kp1 + (size_t)m0 * 64);
        *(short8*)&vt_s[0][lk0] = *(const short8*)(Vp0 + m0);
        *(short8*)&vt_s[0][lk1] = *(const short8*)(Vp1 + m0);
    }

    for (int j = 0; j < 32; ++j) {
        const int cur = j & 1;
        const int mn = m_beg + (((roff + j + 1) & 31) << 6);
        short8 pk0v = *(const short8*)(Kp0 + (size_t)mn * 64);
        short8 pk1v = *(const short8*)(Kp1 + (size_t)mn * 64);
        short8 pv0v = *(const short8*)(Vp0 + mn);
        short8 pv1v = *(const short8*)(Vp1 + mn);
        __syncthreads();

#pragma unroll
        for (int mt = 0; mt < 4; ++mt) {
            const u16* kp = &kt_s[cur][(mt * 16 + l15) * 72 + quad * 8];
            const short8 ka0 = *(const short8*)kp;
            const short8 ka1 = *(const short8*)(kp + 32);
#pragma unroll
            for (int t2 = 0; t2 < 2; ++t2) {
                floatx4 acc = {0.f, 0.f, 0.f, 0.f};
                acc = MFMA16(ka0, aq[t2][0], acc);
                acc = MFMA16(ka1, aq[t2][1], acc);
                const float e0 = __expf(acc[0]), e1 = __expf(acc[1]);
                const float e2 = __expf(acc[2]), e3 = __expf(acc[3]);
                dacc[t2] += (e0 + e1) + (e2 + e3);
                *(uint2*)&p_s[pw + (t2 * 16 + l15) * 72 + mt * 16 + quad * 4] =
                    make_uint2(pk2(e0, e1), pk2(e2, e3));
            }
        }

        short8 pb2[2][2];
#pragma unroll
        for (int t2 = 0; t2 < 2; ++t2)
#pragma unroll
            for (int s = 0; s < 2; ++s)
                pb2[t2][s] = *(const short8*)&p_s[pw + (t2 * 16 + l15) * 72 + s * 32 + quad * 8];
#pragma unroll
        for (int it = 0; it < 4; ++it) {
            const u16* vp = &vt_s[cur][(it * 16 + l15) * 72 + quad * 8];
            const short8 va0 = *(const short8*)vp;
            const short8 va1 = *(const short8*)(vp + 32);
#pragma unroll
            for (int t2 = 0; t2 < 2; ++t2) {
                oacc[it][t2] = MFMA16(va0, pb2[t2][0], oacc[it][t2]);
                oacc[it][t2] = MFMA16(va1, pb2[t2][1], oacc[it][t2]);
            }
        }

        *(short8*)&kt_s[cur ^ 1][lk0] = pk0v;
        *(short8*)&kt_s[cur ^ 1][lk1] = pk1v;
        *(short8*)&vt_s[cur ^ 1][lk0] = pv0v;
        *(short8*)&vt_s[cur ^ 1][lk1] = pv1v;
    }

#pragma unroll
    for (int t2 = 0; t2 < 2; ++t2) {
        float d = dacc[t2];
        d += __shfl_xor(d, 16, 64);
        d += __shfl_xor(d, 32, 64);
        if (quad == 0) deno[qb + w * 32 + t2 * 16 + l15] = d;
    }

#pragma unroll
    for (int it = 0; it < 4; ++it)
#pragma unroll
        for (int t2 = 0; t2 < 2; ++t2) {
            *(uint2*)&p_s[pw + (t2 * 16 + l15) * 72 + it * 16 + quad * 4] =
                make_uint2(pk2(oacc[it][t2][0], oacc[it][t2][1]),
                           pk2(oacc[it][t2][2], oacc[it][t2][3]));
        }
    __syncthreads();
#pragma unroll
    for (int ch = t; ch < 1024; ch += 256) {
        const int row = ch >> 3, cg = ch & 7;
        *(short8*)(numo + (size_t)(qb + row) * 64 + cg * 8) =
            *(const short8*)&p_s[(row >> 5) * 2304 + (row & 31) * 72 + cg * 8];
    }
}

// ---------------------------------------------------------------------------
// K3: epilogue + split-K reduce; n-tile 16, grid (256,4). fp32 weights
// converted at fragment build (pack8).
// ---------------------------------------------------------------------------
__global__ __launch_bounds__(256) void k_epi(
    const u16* __restrict__ num, const float* __restrict__ den,
    const float* __restrict__ wWl, const float* __restrict__ gWl,
    const float* __restrict__ betaWl,
    const float* __restrict__ wW, const float* __restrict__ bW,
    const float* __restrict__ gW, const float* __restrict__ betaW,
    const float* __restrict__ x, float* __restrict__ out)
{
    __shared__ __align__(16) u16 yl_s[16 * 72];
    __shared__ __align__(16) u16 ynl_s[16 * 72];
    __shared__ __align__(16) u16 yy_s[16 * 72];
    const int b = blockIdx.y, n0 = blockIdx.x * 16;
    const int t = threadIdx.x, w = t >> 6, lane = t & 63;
    const int quad = lane >> 4, l15 = lane & 15;
    const size_t ybase = ((size_t)b << 18) + (size_t)n0 * 64;

    if (t < 128) {
        const int row = t >> 3, cg = t & 7;
        const float dn = den[b * 4096 + n0 + row] + den[16384 + b * 4096 + n0 + row];
        const float dl = den[32768 + b * 4096 + n0 + row] + den[49152 + b * 4096 + n0 + row];
        const float inl = 1.0f / dn, ilo = 1.0f / dl;
        const short8 a0 = *(const short8*)(num + ybase + row * 64 + cg * 8);
        const short8 a1 = *(const short8*)(num + SZ_P + ybase + row * 64 + cg * 8);
        const short8 c0 = *(const short8*)(num + 2 * SZ_P + ybase + row * 64 + cg * 8);
        const short8 c1 = *(const short8*)(num + 3 * SZ_P + ybase + row * 64 + cg * 8);
        short8 ynl8, yl8;
#pragma unroll
        for (int j = 0; j < 8; ++j) {
            ynl8[j] = (short)f2bf((bf2f((u16)a0[j]) + bf2f((u16)a1[j])) * inl);
            yl8[j]  = (short)f2bf((bf2f((u16)c0[j]) + bf2f((u16)c1[j])) * ilo);
        }
        *(short8*)&ynl_s[row * 72 + cg * 8] = ynl8;
        *(short8*)&yl_s[row * 72 + cg * 8] = yl8;
    }
    __syncthreads();
    const float rsq = rsqrtf(1.0f + 1e-5f);

    // E1: yy[n][io] = bn(relu(wWl . y_l)) + y_nl
    {
        const short8 a0 = pack8(wWl + (w * 16 + l15) * 64 + quad * 8);
        const short8 a1 = pack8(wWl + (w * 16 + l15) * 64 + 32 + quad * 8);
        float sc[4], bt[4];
#pragma unroll
        for (int r = 0; r < 4; ++r) {
            const int io = w * 16 + quad * 4 + r;
            sc[r] = gWl[io] * rsq;
            bt[r] = betaWl[io];
        }
        floatx4 acc = {0.f, 0.f, 0.f, 0.f};
        const u16* bp_ = &yl_s[l15 * 72 + quad * 8];
        acc = MFMA16(a0, *(const short8*)bp_, acc);
        acc = MFMA16(a1, *(const short8*)(bp_ + 32), acc);
#pragma unroll
        for (int r = 0; r < 4; ++r) {
            const int io = w * 16 + quad * 4 + r;
            float val = fmaxf(acc[r], 0.f) * sc[r] + bt[r];
            val += bf2f(ynl_s[l15 * 72 + io]);
            yy_s[l15 * 72 + io] = f2bf(val);
        }
    }
    __syncthreads();

    // E2: out[c][n] = bn(relu(wW . yy + bW)) + x ; full c-range
#pragma unroll
    for (int rb = 0; rb < 2; ++rb) {
        const int c0 = rb * 64 + w * 16;
        const short8 a0 = pack8(wW + (c0 + l15) * 64 + quad * 8);
        const short8 a1 = pack8(wW + (c0 + l15) * 64 + 32 + quad * 8);
        float bs[4], sc[4], bt[4];
#pragma unroll
        for (int r = 0; r < 4; ++r) {
            const int c = c0 + quad * 4 + r;
            bs[r] = bW[c];
            sc[r] = gW[c] * rsq;
            bt[r] = betaW[c];
        }
        floatx4 acc = {0.f, 0.f, 0.f, 0.f};
        const u16* bp_ = &yy_s[l15 * 72 + quad * 8];
        acc = MFMA16(a0, *(const short8*)bp_, acc);
        acc = MFMA16(a1, *(const short8*)(bp_ + 32), acc);
#pragma unroll
        for (int r = 0; r < 4; ++r) {
            const int c = c0 + quad * 4 + r;
            float val = fmaxf(acc[r] + bs[r], 0.f) * sc[r] + bt[r];
            const size_t xi = ((size_t)b << 19) + ((size_t)c << 12) + n0 + l15;
            out[xi] = val + x[xi];
        }
    }
}

// ---------------------------------------------------------------------------
extern "C" void kernel_launch(void* const* d_in, const int* in_sizes, int n_in,
                              void* d_out, int out_size, void* d_ws, size_t ws_size,
                              hipStream_t stream) {
    const float* x      = (const float*)d_in[0];
    const float* mask   = (const float*)d_in[1];
    const float* wt_nl  = (const float*)d_in[2];  const float* bt_nl = (const float*)d_in[3];
    const float* wp_nl  = (const float*)d_in[4];  const float* bp_nl = (const float*)d_in[5];
    const float* wt_l   = (const float*)d_in[6];  const float* bt_l  = (const float*)d_in[7];
    const float* wp_l   = (const float*)d_in[8];  const float* bp_l  = (const float*)d_in[9];
    const float* wg_nl  = (const float*)d_in[10]; const float* bg_nl = (const float*)d_in[11];
    const float* wg_l   = (const float*)d_in[12]; const float* bg_l  = (const float*)d_in[13];
    const float* wW     = (const float*)d_in[14]; const float* bW    = (const float*)d_in[15];
    const float* gW     = (const float*)d_in[16]; const float* betaW = (const float*)d_in[17];
    const float* wWl    = (const float*)d_in[18]; const float* gWl   = (const float*)d_in[19];
    const float* betaWl = (const float*)d_in[20];

    // ws: 6 qkv (12MB) + num 4x2MB + den 256KB ~= 20.5 MB
    u16* ws  = (u16*)d_ws;
    u16* q0  = ws;
    u16* k0  = q0 + SZ_P;
    u16* v0  = k0 + SZ_P;
    u16* q1  = v0 + SZ_P;
    u16* k1  = q1 + SZ_P;
    u16* v1  = k1 + SZ_P;
    u16* num = v1 + SZ_P;           // 4 x SZ_P (z-major: nl0,nl1,lo0,lo1)
    float* den = (float*)(num + 4 * SZ_P);  // 4 x 16384 fp32

    k_proj<<<dim3(64, 4, 2), 256, 0, stream>>>(x, mask,
        wt_nl, bt_nl, wp_nl, bp_nl, wg_nl, bg_nl,
        wt_l,  bt_l,  wp_l,  bp_l,  wg_l,  bg_l,
        q0, k0, v0, q1, k1, v1);
    k_flash<<<dim3(512), 256, 0, stream>>>(q0, k0, v0, q1, k1, v1, num, den);
    k_epi<<<dim3(256, 4), 256, 0, stream>>>(num, den, wWl, gWl, betaWl,
                                            wW, bW, gW, betaW, x, (float*)d_out);
}

// Round 15
// 184.932 us; speedup vs baseline: 2.6568x; 1.0257x over previous
//
#include <hip/hip_runtime.h>

typedef unsigned short u16;
typedef __attribute__((ext_vector_type(8))) short short8;
typedef __attribute__((ext_vector_type(4))) float floatx4;

#define MFMA16(a, b, c) __builtin_amdgcn_mfma_f32_16x16x32_bf16((a), (b), (c), 0, 0, 0)
#define LOG2E 1.44269504088896340736f

// B=4, C=128, I=64, N=4096. fp32 I/O; bf16 intermediates.
#define SZ_P ((size_t)4 * 64 * 4096)   // 1,048,576 el

__device__ __forceinline__ float bf2f(u16 u) {
    union { unsigned int i; float f; } v; v.i = ((unsigned int)u) << 16; return v.f;
}
__device__ __forceinline__ u16 f2bf(float f) {
    union { float f; unsigned int i; } v; v.f = f;
    unsigned int r = v.i + 0x7fffu + ((v.i >> 16) & 1u);
    return (u16)(r >> 16);
}
__device__ __forceinline__ short8 pack8(const float* __restrict__ p) {
    short8 r;
#pragma unroll
    for (int j = 0; j < 8; ++j) r[j] = (short)f2bf(p[j]);
    return r;
}
// truncation pack: 2 fp32 -> packed bf16x2 (bias cancels in softmax ratio)
__device__ __forceinline__ unsigned int pk2(float a, float b) {
    union { float f; unsigned int u; } x, y; x.f = a; y.f = b;
    return (x.u >> 16) | (y.u & 0xffff0000u);
}

// ---------------------------------------------------------------------------
// K1: both branches' projections (z = branch), in-LDS x transpose.
// Q is pre-scaled by log2(e) so flash can use native exp2.
// q,k bf16 [B,N,I]; v bf16 [B,I,N].
// ---------------------------------------------------------------------------
__global__ __launch_bounds__(256) void k_proj(
    const float* __restrict__ x, const float* __restrict__ mask,
    const float* __restrict__ wq0, const float* __restrict__ bq0,
    const float* __restrict__ wk0, const float* __restrict__ bk0,
    const float* __restrict__ wv0, const float* __restrict__ bv0,
    const float* __restrict__ wq1, const float* __restrict__ bq1,
    const float* __restrict__ wk1, const float* __restrict__ bk1,
    const float* __restrict__ wv1, const float* __restrict__ bv1,
    u16* __restrict__ q0, u16* __restrict__ k0, u16* __restrict__ v0,
    u16* __restrict__ q1, u16* __restrict__ k1, u16* __restrict__ v1)
{
    __shared__ __align__(16) u16 xt_s[64 * 136];  // [n][c] bf16, pad 128->136
    const int n0 = blockIdx.x * 64, b = blockIdx.y, br = blockIdx.z;
    const float* wq = br ? wq1 : wq0;  const float* bq = br ? bq1 : bq0;
    const float* wk = br ? wk1 : wk0;  const float* bk = br ? bk1 : bk0;
    const float* wv = br ? wv1 : wv0;  const float* bv = br ? bv1 : bv0;
    u16* q = br ? q1 : q0;  u16* k = br ? k1 : k0;  u16* v = br ? v1 : v0;

    const int t = threadIdx.x, w = t >> 6, lane = t & 63;
    const int quad = lane >> 4, l15 = lane & 15;
    const float* xb = x + ((size_t)b << 19);

    for (int idx = t; idx < 8192; idx += 256) {
        const int c = idx >> 6, n = idx & 63;
        xt_s[n * 136 + c] = f2bf(xb[((size_t)c << 12) + n0 + n]);
    }
    __syncthreads();

    short8 ax[4];
#pragma unroll
    for (int cc = 0; cc < 4; ++cc)
        ax[cc] = *(const short8*)&xt_s[(w * 16 + l15) * 136 + quad * 8 + cc * 32];

    float mv[4] = {1.f, 1.f, 1.f, 1.f};
    if (br) {
#pragma unroll
        for (int r = 0; r < 4; ++r)
            mv[r] = mask[((size_t)b << 12) + n0 + w * 16 + quad * 4 + r];
    }

    // Q and K: D[n][i]; Q scaled by log2e
#pragma unroll
    for (int qk = 0; qk < 2; ++qk) {
        const float* wsel = qk ? wk : wq;
        const float* bb = qk ? bk : bq;
        u16* o = qk ? k : q;
        const float qscale = qk ? 1.0f : LOG2E;
#pragma unroll
        for (int ns = 0; ns < 4; ++ns) {
            floatx4 acc = {0.f, 0.f, 0.f, 0.f};
            const float* wp = wsel + (ns * 16 + l15) * 128 + quad * 8;
#pragma unroll
            for (int cc = 0; cc < 4; ++cc)
                acc = MFMA16(ax[cc], pack8(wp + cc * 32), acc);
            const float bias_i = bb[ns * 16 + l15];
#pragma unroll
            for (int r = 0; r < 4; ++r) {
                const float val = (acc[r] + bias_i) * mv[r] * qscale;
                o[((size_t)b << 18) + (size_t)(n0 + w * 16 + quad * 4 + r) * 64
                  + ns * 16 + l15] = f2bf(val);
            }
        }
    }

    // V: D[i][n]
    short8 aw[4];
#pragma unroll
    for (int cc = 0; cc < 4; ++cc)
        aw[cc] = pack8(wv + (w * 16 + l15) * 128 + quad * 8 + cc * 32);
    float bvr[4];
#pragma unroll
    for (int r = 0; r < 4; ++r) bvr[r] = bv[w * 16 + quad * 4 + r];
#pragma unroll
    for (int ns = 0; ns < 4; ++ns) {
        floatx4 acc = {0.f, 0.f, 0.f, 0.f};
#pragma unroll
        for (int cc = 0; cc < 4; ++cc)
            acc = MFMA16(aw[cc],
                *(const short8*)&xt_s[(ns * 16 + l15) * 136 + quad * 8 + cc * 32], acc);
#pragma unroll
        for (int r = 0; r < 4; ++r) {
            v[((size_t)b << 18) + ((size_t)(w * 16 + quad * 4 + r) << 12)
              + n0 + ns * 16 + l15] = f2bf(acc[r] + bvr[r]);
        }
    }
}

// ---------------------------------------------------------------------------
// K2: attention, 512-thread blocks (8 waves share K/V staging -> 4 waves/SIMD
// at 2 blocks/CU), split-K x4. 1-D grid, (b,br,sp) in FAST 5 bits (XCD
// locality). Double-buffered staging, per-block m-rotation, native exp2.
// ---------------------------------------------------------------------------
__global__ __launch_bounds__(512, 4) void k_flash(
    const u16* __restrict__ Q0, const u16* __restrict__ K0,
    const u16* __restrict__ V0,
    const u16* __restrict__ Q1, const u16* __restrict__ K1,
    const u16* __restrict__ V1,
    u16* __restrict__ num, float* __restrict__ den)
{
    __shared__ __align__(16) u16 kt_s[2][64 * 72];   // 18.4 KB
    __shared__ __align__(16) u16 vt_s[2][64 * 72];   // 18.4 KB
    __shared__ __align__(16) u16 p_s[8 * 32 * 72];   // 36.9 KB (per-wave P; O^T at end)

    const int flat = blockIdx.x;
    const int g = flat & 31, tile = flat >> 5;       // 16 q-tiles of 256
    const int b = g >> 3, br = (g >> 2) & 1, sp = g & 3;
    const int z = br * 4 + sp;
    const int qb = tile * 256;
    const size_t base = ((size_t)b << 18);
    const u16* Q = (br ? Q1 : Q0) + base;
    const u16* K = (br ? K1 : K0) + base;
    const u16* V = (br ? V1 : V0) + base;
    u16* numo = num + (size_t)z * SZ_P + base;
    float* deno = den + z * 16384 + b * 4096;

    const int t = threadIdx.x, w = t >> 6, lane = t & 63;
    const int quad = lane >> 4, l15 = lane & 15;
    const int pw = w * 32 * 72;

    // staging: one short8 per thread per buffer (64 rows x 8 col-groups = 512)
    const int r0 = t >> 3, cg8 = (t & 7) * 8;
    const u16* Kp0 = K + (size_t)r0 * 64 + cg8;
    const u16* Vp0 = V + ((size_t)r0 << 12) + cg8;
    const int lk0 = r0 * 72 + cg8;

    short8 aq[2][2];
#pragma unroll
    for (int t2 = 0; t2 < 2; ++t2)
#pragma unroll
        for (int s = 0; s < 2; ++s)
            aq[t2][s] = *(const short8*)(Q + (size_t)(qb + w * 32 + t2 * 16 + l15) * 64
                                         + s * 32 + quad * 8);

    floatx4 oacc[4][2];
#pragma unroll
    for (int it = 0; it < 4; ++it)
#pragma unroll
        for (int t2 = 0; t2 < 2; ++t2) oacc[it][t2] = (floatx4){0.f, 0.f, 0.f, 0.f};
    float dacc[2] = {0.f, 0.f};

    const int roff = tile & 15;          // per-block m-phase rotation (16 tiles)
    const int m_beg = sp * 1024;

    {
        const int m0 = m_beg + (roff << 6);
        *(short8*)&kt_s[0][lk0] = *(const short8*)(Kp0 + (size_t)m0 * 64);
        *(short8*)&vt_s[0][lk0] = *(const short8*)(Vp0 + m0);
    }

    for (int j = 0; j < 16; ++j) {
        const int cur = j & 1;
        const int mn = m_beg + (((roff + j + 1) & 15) << 6);
        short8 pkv = *(const short8*)(Kp0 + (size_t)mn * 64);
        short8 pvv = *(const short8*)(Vp0 + mn);
        __syncthreads();

        // S' = K Q^T tiles + exp2 + packed P writes (per-wave region)
#pragma unroll
        for (int mt = 0; mt < 4; ++mt) {
            const u16* kp = &kt_s[cur][(mt * 16 + l15) * 72 + quad * 8];
            const short8 ka0 = *(const short8*)kp;
            const short8 ka1 = *(const short8*)(kp + 32);
#pragma unroll
            for (int t2 = 0; t2 < 2; ++t2) {
                floatx4 acc = {0.f, 0.f, 0.f, 0.f};
                acc = MFMA16(ka0, aq[t2][0], acc);
                acc = MFMA16(ka1, aq[t2][1], acc);
                const float e0 = exp2f(acc[0]), e1 = exp2f(acc[1]);
                const float e2 = exp2f(acc[2]), e3 = exp2f(acc[3]);
                dacc[t2] += (e0 + e1) + (e2 + e3);
                *(uint2*)&p_s[pw + (t2 * 16 + l15) * 72 + mt * 16 + quad * 4] =
                    make_uint2(pk2(e0, e1), pk2(e2, e3));
            }
        }

        // PV: O^T[i][q] += V[i][m] P'[m][q]
        short8 pb2[2][2];
#pragma unroll
        for (int t2 = 0; t2 < 2; ++t2)
#pragma unroll
            for (int s = 0; s < 2; ++s)
                pb2[t2][s] = *(const short8*)&p_s[pw + (t2 * 16 + l15) * 72 + s * 32 + quad * 8];
#pragma unroll
        for (int it = 0; it < 4; ++it) {
            const u16* vp = &vt_s[cur][(it * 16 + l15) * 72 + quad * 8];
            const short8 va0 = *(const short8*)vp;
            const short8 va1 = *(const short8*)(vp + 32);
#pragma unroll
            for (int t2 = 0; t2 < 2; ++t2) {
                oacc[it][t2] = MFMA16(va0, pb2[t2][0], oacc[it][t2]);
                oacc[it][t2] = MFMA16(va1, pb2[t2][1], oacc[it][t2]);
            }
        }

        *(short8*)&kt_s[cur ^ 1][lk0] = pkv;
        *(short8*)&vt_s[cur ^ 1][lk0] = pvv;
    }

    // denominator partials
#pragma unroll
    for (int t2 = 0; t2 < 2; ++t2) {
        float d = dacc[t2];
        d += __shfl_xor(d, 16, 64);
        d += __shfl_xor(d, 32, 64);
        if (quad == 0) deno[qb + w * 32 + t2 * 16 + l15] = d;
    }

    // O^T (C: row=i-local, col=q-local) -> p_s as [q-local][i]
#pragma unroll
    for (int it = 0; it < 4; ++it)
#pragma unroll
        for (int t2 = 0; t2 < 2; ++t2) {
            *(uint2*)&p_s[pw + (t2 * 16 + l15) * 72 + it * 16 + quad * 4] =
                make_uint2(pk2(oacc[it][t2][0], oacc[it][t2][1]),
                           pk2(oacc[it][t2][2], oacc[it][t2][3]));
        }
    __syncthreads();
#pragma unroll
    for (int ch = t; ch < 2048; ch += 512) {
        const int row = ch >> 3, cg = ch & 7;
        *(short8*)(numo + (size_t)(qb + row) * 64 + cg * 8) =
            *(const short8*)&p_s[(row >> 5) * 2304 + (row & 31) * 72 + cg * 8];
    }
}

// ---------------------------------------------------------------------------
// K3: epilogue + split-K(x4) reduce; n-tile 16, grid (256,4).
// ---------------------------------------------------------------------------
__global__ __launch_bounds__(256) void k_epi(
    const u16* __restrict__ num, const float* __restrict__ den,
    const float* __restrict__ wWl, const float* __restrict__ gWl,
    const float* __restrict__ betaWl,
    const float* __restrict__ wW, const float* __restrict__ bW,
    const float* __restrict__ gW, const float* __restrict__ betaW,
    const float* __restrict__ x, float* __restrict__ out)
{
    __shared__ __align__(16) u16 yl_s[16 * 72];
    __shared__ __align__(16) u16 ynl_s[16 * 72];
    __shared__ __align__(16) u16 yy_s[16 * 72];
    const int b = blockIdx.y, n0 = blockIdx.x * 16;
    const int t = threadIdx.x, w = t >> 6, lane = t & 63;
    const int quad = lane >> 4, l15 = lane & 15;
    const size_t ybase = ((size_t)b << 18) + (size_t)n0 * 64;

    if (t < 128) {
        const int row = t >> 3, cg = t & 7;
        float dn = 0.f, dl = 0.f;
#pragma unroll
        for (int sp = 0; sp < 4; ++sp) {
            dn += den[sp * 16384 + b * 4096 + n0 + row];
            dl += den[(4 + sp) * 16384 + b * 4096 + n0 + row];
        }
        const float inl = 1.0f / dn, ilo = 1.0f / dl;
        float an[8] = {0, 0, 0, 0, 0, 0, 0, 0}, al[8] = {0, 0, 0, 0, 0, 0, 0, 0};
#pragma unroll
        for (int sp = 0; sp < 4; ++sp) {
            const short8 vn = *(const short8*)(num + (size_t)sp * SZ_P + ybase + row * 64 + cg * 8);
            const short8 vl = *(const short8*)(num + (size_t)(4 + sp) * SZ_P + ybase + row * 64 + cg * 8);
#pragma unroll
            for (int j = 0; j < 8; ++j) {
                an[j] += bf2f((u16)vn[j]);
                al[j] += bf2f((u16)vl[j]);
            }
        }
        short8 ynl8, yl8;
#pragma unroll
        for (int j = 0; j < 8; ++j) {
            ynl8[j] = (short)f2bf(an[j] * inl);
            yl8[j]  = (short)f2bf(al[j] * ilo);
        }
        *(short8*)&ynl_s[row * 72 + cg * 8] = ynl8;
        *(short8*)&yl_s[row * 72 + cg * 8] = yl8;
    }
    __syncthreads();
    const float rsq = rsqrtf(1.0f + 1e-5f);

    // E1: yy[n][io] = bn(relu(wWl . y_l)) + y_nl
    {
        const short8 a0 = pack8(wWl + (w * 16 + l15) * 64 + quad * 8);
        const short8 a1 = pack8(wWl + (w * 16 + l15) * 64 + 32 + quad * 8);
        float sc[4], bt[4];
#pragma unroll
        for (int r = 0; r < 4; ++r) {
            const int io = w * 16 + quad * 4 + r;
            sc[r] = gWl[io] * rsq;
            bt[r] = betaWl[io];
        }
        floatx4 acc = {0.f, 0.f, 0.f, 0.f};
        const u16* bp_ = &yl_s[l15 * 72 + quad * 8];
        acc = MFMA16(a0, *(const short8*)bp_, acc);
        acc = MFMA16(a1, *(const short8*)(bp_ + 32), acc);
#pragma unroll
        for (int r = 0; r < 4; ++r) {
            const int io = w * 16 + quad * 4 + r;
            float val = fmaxf(acc[r], 0.f) * sc[r] + bt[r];
            val += bf2f(ynl_s[l15 * 72 + io]);
            yy_s[l15 * 72 + io] = f2bf(val);
        }
    }
    __syncthreads();

    // E2: out[c][n] = bn(relu(wW . yy + bW)) + x
#pragma unroll
    for (int rb = 0; rb < 2; ++rb) {
        const int c0 = rb * 64 + w * 16;
        const short8 a0 = pack8(wW + (c0 + l15) * 64 + quad * 8);
        const short8 a1 = pack8(wW + (c0 + l15) * 64 + 32 + quad * 8);
        float bs[4], sc[4], bt[4];
#pragma unroll
        for (int r = 0; r < 4; ++r) {
            const int c = c0 + quad * 4 + r;
            bs[r] = bW[c];
            sc[r] = gW[c] * rsq;
            bt[r] = betaW[c];
        }
        floatx4 acc = {0.f, 0.f, 0.f, 0.f};
        const u16* bp_ = &yy_s[l15 * 72 + quad * 8];
        acc = MFMA16(a0, *(const short8*)bp_, acc);
        acc = MFMA16(a1, *(const short8*)(bp_ + 32), acc);
#pragma unroll
        for (int r = 0; r < 4; ++r) {
            const int c = c0 + quad * 4 + r;
            float val = fmaxf(acc[r] + bs[r], 0.f) * sc[r] + bt[r];
            const size_t xi = ((size_t)b << 19) + ((size_t)c << 12) + n0 + l15;
            out[xi] = val + x[xi];
        }
    }
}

// ---------------------------------------------------------------------------
extern "C" void kernel_launch(void* const* d_in, const int* in_sizes, int n_in,
                              void* d_out, int out_size, void* d_ws, size_t ws_size,
                              hipStream_t stream) {
    const float* x      = (const float*)d_in[0];
    const float* mask   = (const float*)d_in[1];
    const float* wt_nl  = (const float*)d_in[2];  const float* bt_nl = (const float*)d_in[3];
    const float* wp_nl  = (const float*)d_in[4];  const float* bp_nl = (const float*)d_in[5];
    const float* wt_l   = (const float*)d_in[6];  const float* bt_l  = (const float*)d_in[7];
    const float* wp_l   = (const float*)d_in[8];  const float* bp_l  = (const float*)d_in[9];
    const float* wg_nl  = (const float*)d_in[10]; const float* bg_nl = (const float*)d_in[11];
    const float* wg_l   = (const float*)d_in[12]; const float* bg_l  = (const float*)d_in[13];
    const float* wW     = (const float*)d_in[14]; const float* bW    = (const float*)d_in[15];
    const float* gW     = (const float*)d_in[16]; const float* betaW = (const float*)d_in[17];
    const float* wWl    = (const float*)d_in[18]; const float* gWl   = (const float*)d_in[19];
    const float* betaWl = (const float*)d_in[20];

    // ws: 6 qkv (12.6MB) + num 8x2MB (16.8MB) + den 512KB ~= 29.9 MB
    u16* ws  = (u16*)d_ws;
    u16* q0  = ws;
    u16* k0  = q0 + SZ_P;
    u16* v0  = k0 + SZ_P;
    u16* q1  = v0 + SZ_P;
    u16* k1  = q1 + SZ_P;
    u16* v1  = k1 + SZ_P;
    u16* num = v1 + SZ_P;           // 8 x SZ_P (z = br*4+sp)
    float* den = (float*)(num + 8 * SZ_P);  // 8 x 16384 fp32

    k_proj<<<dim3(64, 4, 2), 256, 0, stream>>>(x, mask,
        wt_nl, bt_nl, wp_nl, bp_nl, wg_nl, bg_nl,
        wt_l,  bt_l,  wp_l,  bp_l,  wg_l,  bg_l,
        q0, k0, v0, q1, k1, v1);
    k_flash<<<dim3(512), 512, 0, stream>>>(q0, k0, v0, q1, k1, v1, num, den);
    k_epi<<<dim3(256, 4), 256, 0, stream>>>(num, den, wWl, gWl, betaWl,
                                            wW, bW, gW, betaW, x, (float*)d_out);
}

// Round 16
// 179.662 us; speedup vs baseline: 2.7348x; 1.0293x over previous
//
#include <hip/hip_runtime.h>
#include <hip/hip_bf16.h>

typedef unsigned short u16;
typedef __attribute__((ext_vector_type(8))) short short8;
typedef __attribute__((ext_vector_type(4))) float floatx4;

#define MFMA16(a, b, c) __builtin_amdgcn_mfma_f32_16x16x32_bf16((a), (b), (c), 0, 0, 0)
#define LOG2E 1.44269504088896340736f

// B=4, C=128, I=64, N=4096. fp32 I/O; bf16 intermediates.
#define SZ_P ((size_t)4 * 64 * 4096)   // 1,048,576 el

__device__ __forceinline__ float bf2f(u16 u) {
    union { unsigned int i; float f; } v; v.i = ((unsigned int)u) << 16; return v.f;
}
__device__ __forceinline__ u16 f2bf(float f) {
    union { float f; unsigned int i; } v; v.f = f;
    unsigned int r = v.i + 0x7fffu + ((v.i >> 16) & 1u);
    return (u16)(r >> 16);
}
// packed bf16x2 convert (v_cvt_pk_bf16_f32 on gfx950)
__device__ __forceinline__ unsigned int pk2(float a, float b) {
    union { __hip_bfloat162 h; unsigned int u; } v;
    v.h = __float22bfloat162_rn(make_float2(a, b));
    return v.u;
}

// ---------------------------------------------------------------------------
// P0: weights fp32 -> bf16. wbf: 6 x 8192 (wq0,wk0,wv0,wq1,wk1,wv1),
// wWl @49152 (4096), wW @53248 (8192). Total 61440 el.
// ---------------------------------------------------------------------------
__global__ __launch_bounds__(256) void k_prep_w(
    const float* __restrict__ w0, const float* __restrict__ w1,
    const float* __restrict__ w2, const float* __restrict__ w3,
    const float* __restrict__ w4, const float* __restrict__ w5,
    const float* __restrict__ wWl, const float* __restrict__ wW,
    u16* __restrict__ wbf)
{
    const int idx = blockIdx.x * 256 + threadIdx.x;
    float v;
    if (idx < 49152) {
        const int j = idx >> 13, off = idx & 8191;
        const float* s = (j == 0) ? w0 : (j == 1) ? w1 : (j == 2) ? w2
                       : (j == 3) ? w3 : (j == 4) ? w4 : w5;
        v = s[off];
    } else if (idx < 53248) {
        v = wWl[idx - 49152];
    } else {
        v = wW[idx - 53248];
    }
    wbf[idx] = f2bf(v);
}

// ---------------------------------------------------------------------------
// K1: projections; z = branch*2 + ns-half; in-LDS x transpose; bf16 weights.
// Q pre-scaled by log2e. q,k bf16 [B,N,I]; v bf16 [B,I,N].
// ---------------------------------------------------------------------------
__global__ __launch_bounds__(256) void k_proj(
    const float* __restrict__ x, const float* __restrict__ mask,
    const u16* __restrict__ wbf,
    const float* __restrict__ bq0f, const float* __restrict__ bk0f,
    const float* __restrict__ bv0f,
    const float* __restrict__ bq1f, const float* __restrict__ bk1f,
    const float* __restrict__ bv1f,
    u16* __restrict__ q0, u16* __restrict__ k0, u16* __restrict__ v0,
    u16* __restrict__ q1, u16* __restrict__ k1, u16* __restrict__ v1)
{
    __shared__ __align__(16) u16 xt_s[64 * 136];  // [n][c] bf16, pad 128->136
    const int n0 = blockIdx.x * 64, b = blockIdx.y;
    const int br = blockIdx.z >> 1, half = blockIdx.z & 1;
    const u16* wq = wbf + br * 24576;
    const u16* wk = wq + 8192;
    const u16* wv = wk + 8192;
    const float* bq = br ? bq1f : bq0f;
    const float* bk = br ? bk1f : bk0f;
    const float* bv = br ? bv1f : bv0f;
    u16* q = br ? q1 : q0;  u16* k = br ? k1 : k0;  u16* v = br ? v1 : v0;

    const int t = threadIdx.x, w = t >> 6, lane = t & 63;
    const int quad = lane >> 4, l15 = lane & 15;
    const float* xb = x + ((size_t)b << 19);

    for (int idx = t; idx < 8192; idx += 256) {
        const int c = idx >> 6, n = idx & 63;
        xt_s[n * 136 + c] = f2bf(xb[((size_t)c << 12) + n0 + n]);
    }
    __syncthreads();

    short8 ax[4];
#pragma unroll
    for (int cc = 0; cc < 4; ++cc)
        ax[cc] = *(const short8*)&xt_s[(w * 16 + l15) * 136 + quad * 8 + cc * 32];

    float mv[4] = {1.f, 1.f, 1.f, 1.f};
    if (br) {
#pragma unroll
        for (int r = 0; r < 4; ++r)
            mv[r] = mask[((size_t)b << 12) + n0 + w * 16 + quad * 4 + r];
    }

    // Q and K: D[n][i], i-cols = this half's 32; Q scaled by log2e
#pragma unroll
    for (int qk = 0; qk < 2; ++qk) {
        const u16* wsel = qk ? wk : wq;
        const float* bb = qk ? bk : bq;
        u16* o = qk ? k : q;
        const float qscale = qk ? 1.0f : LOG2E;
#pragma unroll
        for (int nsh = 0; nsh < 2; ++nsh) {
            const int ns = half * 2 + nsh;
            floatx4 acc = {0.f, 0.f, 0.f, 0.f};
            const u16* wp = wsel + (ns * 16 + l15) * 128 + quad * 8;
#pragma unroll
            for (int cc = 0; cc < 4; ++cc)
                acc = MFMA16(ax[cc], *(const short8*)(wp + cc * 32), acc);
            const float bias_i = bb[ns * 16 + l15];
#pragma unroll
            for (int r = 0; r < 4; ++r) {
                const float val = (acc[r] + bias_i) * mv[r] * qscale;
                o[((size_t)b << 18) + (size_t)(n0 + w * 16 + quad * 4 + r) * 64
                  + ns * 16 + l15] = f2bf(val);
            }
        }
    }

    // V: D[i][n], n-cols = this half's 32
    short8 aw[4];
#pragma unroll
    for (int cc = 0; cc < 4; ++cc)
        aw[cc] = *(const short8*)(wv + (w * 16 + l15) * 128 + quad * 8 + cc * 32);
    float bvr[4];
#pragma unroll
    for (int r = 0; r < 4; ++r) bvr[r] = bv[w * 16 + quad * 4 + r];
#pragma unroll
    for (int nsh = 0; nsh < 2; ++nsh) {
        const int ns = half * 2 + nsh;
        floatx4 acc = {0.f, 0.f, 0.f, 0.f};
#pragma unroll
        for (int cc = 0; cc < 4; ++cc)
            acc = MFMA16(aw[cc],
                *(const short8*)&xt_s[(ns * 16 + l15) * 136 + quad * 8 + cc * 32], acc);
#pragma unroll
        for (int r = 0; r < 4; ++r) {
            v[((size_t)b << 18) + ((size_t)(w * 16 + quad * 4 + r) << 12)
              + n0 + ns * 16 + l15] = f2bf(acc[r] + bvr[r]);
        }
    }
}

// ---------------------------------------------------------------------------
// K2: attention, 512-thread blocks (8 waves, 4 waves/SIMD at 2 blocks/CU),
// split-K x4. (b,br,sp) in FAST 5 bits (XCD locality). Double-buffered
// staging, per-block m-rotation, native exp2, packed bf16 converts.
// ---------------------------------------------------------------------------
__global__ __launch_bounds__(512, 4) void k_flash(
    const u16* __restrict__ Q0, const u16* __restrict__ K0,
    const u16* __restrict__ V0,
    const u16* __restrict__ Q1, const u16* __restrict__ K1,
    const u16* __restrict__ V1,
    u16* __restrict__ num, float* __restrict__ den)
{
    __shared__ __align__(16) u16 kt_s[2][64 * 72];   // 18.4 KB
    __shared__ __align__(16) u16 vt_s[2][64 * 72];   // 18.4 KB
    __shared__ __align__(16) u16 p_s[8 * 32 * 72];   // 36.9 KB

    const int flat = blockIdx.x;
    const int g = flat & 31, tile = flat >> 5;       // 16 q-tiles of 256
    const int b = g >> 3, br = (g >> 2) & 1, sp = g & 3;
    const int z = br * 4 + sp;
    const int qb = tile * 256;
    const size_t base = ((size_t)b << 18);
    const u16* Q = (br ? Q1 : Q0) + base;
    const u16* K = (br ? K1 : K0) + base;
    const u16* V = (br ? V1 : V0) + base;
    u16* numo = num + (size_t)z * SZ_P + base;
    float* deno = den + z * 16384 + b * 4096;

    const int t = threadIdx.x, w = t >> 6, lane = t & 63;
    const int quad = lane >> 4, l15 = lane & 15;
    const int pw = w * 32 * 72;

    const int r0 = t >> 3, cg8 = (t & 7) * 8;
    const u16* Kp0 = K + (size_t)r0 * 64 + cg8;
    const u16* Vp0 = V + ((size_t)r0 << 12) + cg8;
    const int lk0 = r0 * 72 + cg8;

    short8 aq[2][2];
#pragma unroll
    for (int t2 = 0; t2 < 2; ++t2)
#pragma unroll
        for (int s = 0; s < 2; ++s)
            aq[t2][s] = *(const short8*)(Q + (size_t)(qb + w * 32 + t2 * 16 + l15) * 64
                                         + s * 32 + quad * 8);

    floatx4 oacc[4][2];
#pragma unroll
    for (int it = 0; it < 4; ++it)
#pragma unroll
        for (int t2 = 0; t2 < 2; ++t2) oacc[it][t2] = (floatx4){0.f, 0.f, 0.f, 0.f};
    float dacc[2] = {0.f, 0.f};

    const int roff = tile & 15;
    const int m_beg = sp * 1024;

    {
        const int m0 = m_beg + (roff << 6);
        *(short8*)&kt_s[0][lk0] = *(const short8*)(Kp0 + (size_t)m0 * 64);
        *(short8*)&vt_s[0][lk0] = *(const short8*)(Vp0 + m0);
    }

    for (int j = 0; j < 16; ++j) {
        const int cur = j & 1;
        const int mn = m_beg + (((roff + j + 1) & 15) << 6);
        short8 pkv = *(const short8*)(Kp0 + (size_t)mn * 64);
        short8 pvv = *(const short8*)(Vp0 + mn);
        __syncthreads();

        // S' = K Q^T tiles + exp2 + packed P writes (per-wave region)
#pragma unroll
        for (int mt = 0; mt < 4; ++mt) {
            const u16* kp = &kt_s[cur][(mt * 16 + l15) * 72 + quad * 8];
            const short8 ka0 = *(const short8*)kp;
            const short8 ka1 = *(const short8*)(kp + 32);
#pragma unroll
            for (int t2 = 0; t2 < 2; ++t2) {
                floatx4 acc = {0.f, 0.f, 0.f, 0.f};
                acc = MFMA16(ka0, aq[t2][0], acc);
                acc = MFMA16(ka1, aq[t2][1], acc);
                const float e0 = exp2f(acc[0]), e1 = exp2f(acc[1]);
                const float e2 = exp2f(acc[2]), e3 = exp2f(acc[3]);
                dacc[t2] += (e0 + e1) + (e2 + e3);
                *(uint2*)&p_s[pw + (t2 * 16 + l15) * 72 + mt * 16 + quad * 4] =
                    make_uint2(pk2(e0, e1), pk2(e2, e3));
            }
        }

        // PV: O^T[i][q] += V[i][m] P'[m][q]
        short8 pb2[2][2];
#pragma unroll
        for (int t2 = 0; t2 < 2; ++t2)
#pragma unroll
            for (int s = 0; s < 2; ++s)
                pb2[t2][s] = *(const short8*)&p_s[pw + (t2 * 16 + l15) * 72 + s * 32 + quad * 8];
#pragma unroll
        for (int it = 0; it < 4; ++it) {
            const u16* vp = &vt_s[cur][(it * 16 + l15) * 72 + quad * 8];
            const short8 va0 = *(const short8*)vp;
            const short8 va1 = *(const short8*)(vp + 32);
#pragma unroll
            for (int t2 = 0; t2 < 2; ++t2) {
                oacc[it][t2] = MFMA16(va0, pb2[t2][0], oacc[it][t2]);
                oacc[it][t2] = MFMA16(va1, pb2[t2][1], oacc[it][t2]);
            }
        }

        *(short8*)&kt_s[cur ^ 1][lk0] = pkv;
        *(short8*)&vt_s[cur ^ 1][lk0] = pvv;
    }

    // denominator partials
#pragma unroll
    for (int t2 = 0; t2 < 2; ++t2) {
        float d = dacc[t2];
        d += __shfl_xor(d, 16, 64);
        d += __shfl_xor(d, 32, 64);
        if (quad == 0) deno[qb + w * 32 + t2 * 16 + l15] = d;
    }

    // O^T (C: row=i-local, col=q-local) -> p_s as [q-local][i]
#pragma unroll
    for (int it = 0; it < 4; ++it)
#pragma unroll
        for (int t2 = 0; t2 < 2; ++t2) {
            *(uint2*)&p_s[pw + (t2 * 16 + l15) * 72 + it * 16 + quad * 4] =
                make_uint2(pk2(oacc[it][t2][0], oacc[it][t2][1]),
                           pk2(oacc[it][t2][2], oacc[it][t2][3]));
        }
    __syncthreads();
#pragma unroll
    for (int ch = t; ch < 2048; ch += 512) {
        const int row = ch >> 3, cg = ch & 7;
        *(short8*)(numo + (size_t)(qb + row) * 64 + cg * 8) =
            *(const short8*)&p_s[(row >> 5) * 2304 + (row & 31) * 72 + cg * 8];
    }
}

// ---------------------------------------------------------------------------
// K3: epilogue + split-K(x4) reduce; n-tile 16, grid (256,4); bf16 weights.
// ---------------------------------------------------------------------------
__global__ __launch_bounds__(256) void k_epi(
    const u16* __restrict__ num, const float* __restrict__ den,
    const u16* __restrict__ wbf,
    const float* __restrict__ gWl, const float* __restrict__ betaWl,
    const float* __restrict__ bW, const float* __restrict__ gW,
    const float* __restrict__ betaW,
    const float* __restrict__ x, float* __restrict__ out)
{
    __shared__ __align__(16) u16 yl_s[16 * 72];
    __shared__ __align__(16) u16 ynl_s[16 * 72];
    __shared__ __align__(16) u16 yy_s[16 * 72];
    const int b = blockIdx.y, n0 = blockIdx.x * 16;
    const int t = threadIdx.x, w = t >> 6, lane = t & 63;
    const int quad = lane >> 4, l15 = lane & 15;
    const size_t ybase = ((size_t)b << 18) + (size_t)n0 * 64;

    if (t < 128) {
        const int row = t >> 3, cg = t & 7;
        float dn = 0.f, dl = 0.f;
#pragma unroll
        for (int sp = 0; sp < 4; ++sp) {
            dn += den[sp * 16384 + b * 4096 + n0 + row];
            dl += den[(4 + sp) * 16384 + b * 4096 + n0 + row];
        }
        const float inl = 1.0f / dn, ilo = 1.0f / dl;
        float an[8] = {0, 0, 0, 0, 0, 0, 0, 0}, al[8] = {0, 0, 0, 0, 0, 0, 0, 0};
#pragma unroll
        for (int sp = 0; sp < 4; ++sp) {
            const short8 vn = *(const short8*)(num + (size_t)sp * SZ_P + ybase + row * 64 + cg * 8);
            const short8 vl = *(const short8*)(num + (size_t)(4 + sp) * SZ_P + ybase + row * 64 + cg * 8);
#pragma unroll
            for (int j = 0; j < 8; ++j) {
                an[j] += bf2f((u16)vn[j]);
                al[j] += bf2f((u16)vl[j]);
            }
        }
        short8 ynl8, yl8;
#pragma unroll
        for (int j = 0; j < 8; ++j) {
            ynl8[j] = (short)f2bf(an[j] * inl);
            yl8[j]  = (short)f2bf(al[j] * ilo);
        }
        *(short8*)&ynl_s[row * 72 + cg * 8] = ynl8;
        *(short8*)&yl_s[row * 72 + cg * 8] = yl8;
    }
    __syncthreads();
    const float rsq = rsqrtf(1.0f + 1e-5f);
    const u16* wblW = wbf + 49152;
    const u16* wbW  = wbf + 53248;

    // E1: yy[n][io] = bn(relu(wWl . y_l)) + y_nl
    {
        const short8 a0 = *(const short8*)(wblW + (w * 16 + l15) * 64 + quad * 8);
        const short8 a1 = *(const short8*)(wblW + (w * 16 + l15) * 64 + 32 + quad * 8);
        float sc[4], bt[4];
#pragma unroll
        for (int r = 0; r < 4; ++r) {
            const int io = w * 16 + quad * 4 + r;
            sc[r] = gWl[io] * rsq;
            bt[r] = betaWl[io];
        }
        floatx4 acc = {0.f, 0.f, 0.f, 0.f};
        const u16* bp_ = &yl_s[l15 * 72 + quad * 8];
        acc = MFMA16(a0, *(const short8*)bp_, acc);
        acc = MFMA16(a1, *(const short8*)(bp_ + 32), acc);
#pragma unroll
        for (int r = 0; r < 4; ++r) {
            const int io = w * 16 + quad * 4 + r;
            float val = fmaxf(acc[r], 0.f) * sc[r] + bt[r];
            val += bf2f(ynl_s[l15 * 72 + io]);
            yy_s[l15 * 72 + io] = f2bf(val);
        }
    }
    __syncthreads();

    // E2: out[c][n] = bn(relu(wW . yy + bW)) + x
#pragma unroll
    for (int rb = 0; rb < 2; ++rb) {
        const int c0 = rb * 64 + w * 16;
        const short8 a0 = *(const short8*)(wbW + (c0 + l15) * 64 + quad * 8);
        const short8 a1 = *(const short8*)(wbW + (c0 + l15) * 64 + 32 + quad * 8);
        float bs[4], sc[4], bt[4];
#pragma unroll
        for (int r = 0; r < 4; ++r) {
            const int c = c0 + quad * 4 + r;
            bs[r] = bW[c];
            sc[r] = gW[c] * rsq;
            bt[r] = betaW[c];
        }
        floatx4 acc = {0.f, 0.f, 0.f, 0.f};
        const u16* bp_ = &yy_s[l15 * 72 + quad * 8];
        acc = MFMA16(a0, *(const short8*)bp_, acc);
        acc = MFMA16(a1, *(const short8*)(bp_ + 32), acc);
#pragma unroll
        for (int r = 0; r < 4; ++r) {
            const int c = c0 + quad * 4 + r;
            float val = fmaxf(acc[r] + bs[r], 0.f) * sc[r] + bt[r];
            const size_t xi = ((size_t)b << 19) + ((size_t)c << 12) + n0 + l15;
            out[xi] = val + x[xi];
        }
    }
}

// ---------------------------------------------------------------------------
extern "C" void kernel_launch(void* const* d_in, const int* in_sizes, int n_in,
                              void* d_out, int out_size, void* d_ws, size_t ws_size,
                              hipStream_t stream) {
    const float* x      = (const float*)d_in[0];
    const float* mask   = (const float*)d_in[1];
    const float* wt_nl  = (const float*)d_in[2];  const float* bt_nl = (const float*)d_in[3];
    const float* wp_nl  = (const float*)d_in[4];  const float* bp_nl = (const float*)d_in[5];
    const float* wt_l   = (const float*)d_in[6];  const float* bt_l  = (const float*)d_in[7];
    const float* wp_l   = (const float*)d_in[8];  const float* bp_l  = (const float*)d_in[9];
    const float* wg_nl  = (const float*)d_in[10]; const float* bg_nl = (const float*)d_in[11];
    const float* wg_l   = (const float*)d_in[12]; const float* bg_l  = (const float*)d_in[13];
    const float* wW     = (const float*)d_in[14]; const float* bW    = (const float*)d_in[15];
    const float* gW     = (const float*)d_in[16]; const float* betaW = (const float*)d_in[17];
    const float* wWl    = (const float*)d_in[18]; const float* gWl   = (const float*)d_in[19];
    const float* betaWl = (const float*)d_in[20];

    // ws: wbf 120KB + 6 qkv (12.6MB) + num 8x2MB (16.8MB) + den 512KB ~= 30 MB
    u16* ws  = (u16*)d_ws;
    u16* wbf = ws;                  // 61440
    u16* q0  = wbf + 61440;
    u16* k0  = q0 + SZ_P;
    u16* v0  = k0 + SZ_P;
    u16* q1  = v0 + SZ_P;
    u16* k1  = q1 + SZ_P;
    u16* v1  = k1 + SZ_P;
    u16* num = v1 + SZ_P;           // 8 x SZ_P (z = br*4+sp)
    float* den = (float*)(num + 8 * SZ_P);  // 8 x 16384 fp32

    k_prep_w<<<dim3(240), 256, 0, stream>>>(wt_nl, wp_nl, wg_nl,
                                            wt_l, wp_l, wg_l, wWl, wW, wbf);
    k_proj<<<dim3(64, 4, 4), 256, 0, stream>>>(x, mask, wbf,
        bt_nl, bp_nl, bg_nl, bt_l, bp_l, bg_l,
        q0, k0, v0, q1, k1, v1);
    k_flash<<<dim3(512), 512, 0, stream>>>(q0, k0, v0, q1, k1, v1, num, den);
    k_epi<<<dim3(256, 4), 256, 0, stream>>>(num, den, wbf, gWl, betaWl,
                                            bW, gW, betaW, x, (float*)d_out);
}

// Round 17
// 175.465 us; speedup vs baseline: 2.8002x; 1.0239x over previous
//
#include <hip/hip_runtime.h>

typedef unsigned short u16;
typedef __attribute__((ext_vector_type(8))) short short8;
typedef __attribute__((ext_vector_type(4))) float floatx4;

#define MFMA16(a, b, c) __builtin_amdgcn_mfma_f32_16x16x32_bf16((a), (b), (c), 0, 0, 0)
#define LOG2E 1.44269504088896340736f

// B=4, C=128, I=64, N=4096. fp32 I/O; bf16 intermediates.
#define SZ_P ((size_t)4 * 64 * 4096)   // 1,048,576 el

__device__ __forceinline__ float bf2f(u16 u) {
    union { unsigned int i; float f; } v; v.i = ((unsigned int)u) << 16; return v.f;
}
__device__ __forceinline__ u16 f2bf(float f) {
    union { float f; unsigned int i; } v; v.f = f;
    unsigned int r = v.i + 0x7fffu + ((v.i >> 16) & 1u);
    return (u16)(r >> 16);
}
// truncation pack: 2 fp32 -> packed bf16x2 (bias cancels in softmax ratio)
__device__ __forceinline__ unsigned int pk2(float a, float b) {
    union { float f; unsigned int u; } x, y; x.f = a; y.f = b;
    return (x.u >> 16) | (y.u & 0xffff0000u);
}

// ---------------------------------------------------------------------------
// P0: weights fp32 -> bf16. wbf: 6 x 8192 (wq0,wk0,wv0,wq1,wk1,wv1),
// wWl @49152 (4096), wW @53248 (8192). Total 61440 el.
// ---------------------------------------------------------------------------
__global__ __launch_bounds__(256) void k_prep_w(
    const float* __restrict__ w0, const float* __restrict__ w1,
    const float* __restrict__ w2, const float* __restrict__ w3,
    const float* __restrict__ w4, const float* __restrict__ w5,
    const float* __restrict__ wWl, const float* __restrict__ wW,
    u16* __restrict__ wbf)
{
    const int idx = blockIdx.x * 256 + threadIdx.x;
    float v;
    if (idx < 49152) {
        const int j = idx >> 13, off = idx & 8191;
        const float* s = (j == 0) ? w0 : (j == 1) ? w1 : (j == 2) ? w2
                       : (j == 3) ? w3 : (j == 4) ? w4 : w5;
        v = s[off];
    } else if (idx < 53248) {
        v = wWl[idx - 49152];
    } else {
        v = wW[idx - 53248];
    }
    wbf[idx] = f2bf(v);
}

// ---------------------------------------------------------------------------
// K1: projections; z = branch*2 + ns-half; in-LDS x transpose; bf16 weights.
// Q pre-scaled by log2e. q,k bf16 [B,N,I]; v bf16 [B,I,N].
// ---------------------------------------------------------------------------
__global__ __launch_bounds__(256) void k_proj(
    const float* __restrict__ x, const float* __restrict__ mask,
    const u16* __restrict__ wbf,
    const float* __restrict__ bq0f, const float* __restrict__ bk0f,
    const float* __restrict__ bv0f,
    const float* __restrict__ bq1f, const float* __restrict__ bk1f,
    const float* __restrict__ bv1f,
    u16* __restrict__ q0, u16* __restrict__ k0, u16* __restrict__ v0,
    u16* __restrict__ q1, u16* __restrict__ k1, u16* __restrict__ v1)
{
    __shared__ __align__(16) u16 xt_s[64 * 136];  // [n][c] bf16, pad 128->136
    const int n0 = blockIdx.x * 64, b = blockIdx.y;
    const int br = blockIdx.z >> 1, half = blockIdx.z & 1;
    const u16* wq = wbf + br * 24576;
    const u16* wk = wq + 8192;
    const u16* wv = wk + 8192;
    const float* bq = br ? bq1f : bq0f;
    const float* bk = br ? bk1f : bk0f;
    const float* bv = br ? bv1f : bv0f;
    u16* q = br ? q1 : q0;  u16* k = br ? k1 : k0;  u16* v = br ? v1 : v0;

    const int t = threadIdx.x, w = t >> 6, lane = t & 63;
    const int quad = lane >> 4, l15 = lane & 15;
    const float* xb = x + ((size_t)b << 19);

    for (int idx = t; idx < 8192; idx += 256) {
        const int c = idx >> 6, n = idx & 63;
        xt_s[n * 136 + c] = f2bf(xb[((size_t)c << 12) + n0 + n]);
    }
    __syncthreads();

    short8 ax[4];
#pragma unroll
    for (int cc = 0; cc < 4; ++cc)
        ax[cc] = *(const short8*)&xt_s[(w * 16 + l15) * 136 + quad * 8 + cc * 32];

    float mv[4] = {1.f, 1.f, 1.f, 1.f};
    if (br) {
#pragma unroll
        for (int r = 0; r < 4; ++r)
            mv[r] = mask[((size_t)b << 12) + n0 + w * 16 + quad * 4 + r];
    }

    // Q and K: D[n][i], i-cols = this half's 32; Q scaled by log2e
#pragma unroll
    for (int qk = 0; qk < 2; ++qk) {
        const u16* wsel = qk ? wk : wq;
        const float* bb = qk ? bk : bq;
        u16* o = qk ? k : q;
        const float qscale = qk ? 1.0f : LOG2E;
#pragma unroll
        for (int nsh = 0; nsh < 2; ++nsh) {
            const int ns = half * 2 + nsh;
            floatx4 acc = {0.f, 0.f, 0.f, 0.f};
            const u16* wp = wsel + (ns * 16 + l15) * 128 + quad * 8;
#pragma unroll
            for (int cc = 0; cc < 4; ++cc)
                acc = MFMA16(ax[cc], *(const short8*)(wp + cc * 32), acc);
            const float bias_i = bb[ns * 16 + l15];
#pragma unroll
            for (int r = 0; r < 4; ++r) {
                const float val = (acc[r] + bias_i) * mv[r] * qscale;
                o[((size_t)b << 18) + (size_t)(n0 + w * 16 + quad * 4 + r) * 64
                  + ns * 16 + l15] = f2bf(val);
            }
        }
    }

    // V: D[i][n], n-cols = this half's 32
    short8 aw[4];
#pragma unroll
    for (int cc = 0; cc < 4; ++cc)
        aw[cc] = *(const short8*)(wv + (w * 16 + l15) * 128 + quad * 8 + cc * 32);
    float bvr[4];
#pragma unroll
    for (int r = 0; r < 4; ++r) bvr[r] = bv[w * 16 + quad * 4 + r];
#pragma unroll
    for (int nsh = 0; nsh < 2; ++nsh) {
        const int ns = half * 2 + nsh;
        floatx4 acc = {0.f, 0.f, 0.f, 0.f};
#pragma unroll
        for (int cc = 0; cc < 4; ++cc)
            acc = MFMA16(aw[cc],
                *(const short8*)&xt_s[(ns * 16 + l15) * 136 + quad * 8 + cc * 32], acc);
#pragma unroll
        for (int r = 0; r < 4; ++r) {
            v[((size_t)b << 18) + ((size_t)(w * 16 + quad * 4 + r) << 12)
              + n0 + ns * 16 + l15] = f2bf(acc[r] + bvr[r]);
        }
    }
}

// ---------------------------------------------------------------------------
// K2: attention — r15 body verbatim (best measured: 62.5 us).
// 512-thread blocks (8 waves, 4 waves/SIMD at 2 blocks/CU), split-K x4.
// (b,br,sp) in FAST 5 bits (XCD locality). Double-buffered staging,
// per-block m-rotation, native exp2, truncation bf16 packs.
// ---------------------------------------------------------------------------
__global__ __launch_bounds__(512, 4) void k_flash(
    const u16* __restrict__ Q0, const u16* __restrict__ K0,
    const u16* __restrict__ V0,
    const u16* __restrict__ Q1, const u16* __restrict__ K1,
    const u16* __restrict__ V1,
    u16* __restrict__ num, float* __restrict__ den)
{
    __shared__ __align__(16) u16 kt_s[2][64 * 72];   // 18.4 KB
    __shared__ __align__(16) u16 vt_s[2][64 * 72];   // 18.4 KB
    __shared__ __align__(16) u16 p_s[8 * 32 * 72];   // 36.9 KB

    const int flat = blockIdx.x;
    const int g = flat & 31, tile = flat >> 5;       // 16 q-tiles of 256
    const int b = g >> 3, br = (g >> 2) & 1, sp = g & 3;
    const int z = br * 4 + sp;
    const int qb = tile * 256;
    const size_t base = ((size_t)b << 18);
    const u16* Q = (br ? Q1 : Q0) + base;
    const u16* K = (br ? K1 : K0) + base;
    const u16* V = (br ? V1 : V0) + base;
    u16* numo = num + (size_t)z * SZ_P + base;
    float* deno = den + z * 16384 + b * 4096;

    const int t = threadIdx.x, w = t >> 6, lane = t & 63;
    const int quad = lane >> 4, l15 = lane & 15;
    const int pw = w * 32 * 72;

    const int r0 = t >> 3, cg8 = (t & 7) * 8;
    const u16* Kp0 = K + (size_t)r0 * 64 + cg8;
    const u16* Vp0 = V + ((size_t)r0 << 12) + cg8;
    const int lk0 = r0 * 72 + cg8;

    short8 aq[2][2];
#pragma unroll
    for (int t2 = 0; t2 < 2; ++t2)
#pragma unroll
        for (int s = 0; s < 2; ++s)
            aq[t2][s] = *(const short8*)(Q + (size_t)(qb + w * 32 + t2 * 16 + l15) * 64
                                         + s * 32 + quad * 8);

    floatx4 oacc[4][2];
#pragma unroll
    for (int it = 0; it < 4; ++it)
#pragma unroll
        for (int t2 = 0; t2 < 2; ++t2) oacc[it][t2] = (floatx4){0.f, 0.f, 0.f, 0.f};
    float dacc[2] = {0.f, 0.f};

    const int roff = tile & 15;
    const int m_beg = sp * 1024;

    {
        const int m0 = m_beg + (roff << 6);
        *(short8*)&kt_s[0][lk0] = *(const short8*)(Kp0 + (size_t)m0 * 64);
        *(short8*)&vt_s[0][lk0] = *(const short8*)(Vp0 + m0);
    }

    for (int j = 0; j < 16; ++j) {
        const int cur = j & 1;
        const int mn = m_beg + (((roff + j + 1) & 15) << 6);
        short8 pkv = *(const short8*)(Kp0 + (size_t)mn * 64);
        short8 pvv = *(const short8*)(Vp0 + mn);
        __syncthreads();

        // S' = K Q^T tiles + exp2 + packed P writes (per-wave region)
#pragma unroll
        for (int mt = 0; mt < 4; ++mt) {
            const u16* kp = &kt_s[cur][(mt * 16 + l15) * 72 + quad * 8];
            const short8 ka0 = *(const short8*)kp;
            const short8 ka1 = *(const short8*)(kp + 32);
#pragma unroll
            for (int t2 = 0; t2 < 2; ++t2) {
                floatx4 acc = {0.f, 0.f, 0.f, 0.f};
                acc = MFMA16(ka0, aq[t2][0], acc);
                acc = MFMA16(ka1, aq[t2][1], acc);
                const float e0 = exp2f(acc[0]), e1 = exp2f(acc[1]);
                const float e2 = exp2f(acc[2]), e3 = exp2f(acc[3]);
                dacc[t2] += (e0 + e1) + (e2 + e3);
                *(uint2*)&p_s[pw + (t2 * 16 + l15) * 72 + mt * 16 + quad * 4] =
                    make_uint2(pk2(e0, e1), pk2(e2, e3));
            }
        }

        // PV: O^T[i][q] += V[i][m] P'[m][q]
        short8 pb2[2][2];
#pragma unroll
        for (int t2 = 0; t2 < 2; ++t2)
#pragma unroll
            for (int s = 0; s < 2; ++s)
                pb2[t2][s] = *(const short8*)&p_s[pw + (t2 * 16 + l15) * 72 + s * 32 + quad * 8];
#pragma unroll
        for (int it = 0; it < 4; ++it) {
            const u16* vp = &vt_s[cur][(it * 16 + l15) * 72 + quad * 8];
            const short8 va0 = *(const short8*)vp;
            const short8 va1 = *(const short8*)(vp + 32);
#pragma unroll
            for (int t2 = 0; t2 < 2; ++t2) {
                oacc[it][t2] = MFMA16(va0, pb2[t2][0], oacc[it][t2]);
                oacc[it][t2] = MFMA16(va1, pb2[t2][1], oacc[it][t2]);
            }
        }

        *(short8*)&kt_s[cur ^ 1][lk0] = pkv;
        *(short8*)&vt_s[cur ^ 1][lk0] = pvv;
    }

    // denominator partials
#pragma unroll
    for (int t2 = 0; t2 < 2; ++t2) {
        float d = dacc[t2];
        d += __shfl_xor(d, 16, 64);
        d += __shfl_xor(d, 32, 64);
        if (quad == 0) deno[qb + w * 32 + t2 * 16 + l15] = d;
    }

    // O^T (C: row=i-local, col=q-local) -> p_s as [q-local][i]
#pragma unroll
    for (int it = 0; it < 4; ++it)
#pragma unroll
        for (int t2 = 0; t2 < 2; ++t2) {
            *(uint2*)&p_s[pw + (t2 * 16 + l15) * 72 + it * 16 + quad * 4] =
                make_uint2(pk2(oacc[it][t2][0], oacc[it][t2][1]),
                           pk2(oacc[it][t2][2], oacc[it][t2][3]));
        }
    __syncthreads();
#pragma unroll
    for (int ch = t; ch < 2048; ch += 512) {
        const int row = ch >> 3, cg = ch & 7;
        *(short8*)(numo + (size_t)(qb + row) * 64 + cg * 8) =
            *(const short8*)&p_s[(row >> 5) * 2304 + (row & 31) * 72 + cg * 8];
    }
}

// ---------------------------------------------------------------------------
// K3: epilogue + split-K(x4) reduce; n-tile 16, grid (256,4); bf16 weights.
// ---------------------------------------------------------------------------
__global__ __launch_bounds__(256) void k_epi(
    const u16* __restrict__ num, const float* __restrict__ den,
    const u16* __restrict__ wbf,
    const float* __restrict__ gWl, const float* __restrict__ betaWl,
    const float* __restrict__ bW, const float* __restrict__ gW,
    const float* __restrict__ betaW,
    const float* __restrict__ x, float* __restrict__ out)
{
    __shared__ __align__(16) u16 yl_s[16 * 72];
    __shared__ __align__(16) u16 ynl_s[16 * 72];
    __shared__ __align__(16) u16 yy_s[16 * 72];
    const int b = blockIdx.y, n0 = blockIdx.x * 16;
    const int t = threadIdx.x, w = t >> 6, lane = t & 63;
    const int quad = lane >> 4, l15 = lane & 15;
    const size_t ybase = ((size_t)b << 18) + (size_t)n0 * 64;

    if (t < 128) {
        const int row = t >> 3, cg = t & 7;
        float dn = 0.f, dl = 0.f;
#pragma unroll
        for (int sp = 0; sp < 4; ++sp) {
            dn += den[sp * 16384 + b * 4096 + n0 + row];
            dl += den[(4 + sp) * 16384 + b * 4096 + n0 + row];
        }
        const float inl = 1.0f / dn, ilo = 1.0f / dl;
        float an[8] = {0, 0, 0, 0, 0, 0, 0, 0}, al[8] = {0, 0, 0, 0, 0, 0, 0, 0};
#pragma unroll
        for (int sp = 0; sp < 4; ++sp) {
            const short8 vn = *(const short8*)(num + (size_t)sp * SZ_P + ybase + row * 64 + cg * 8);
            const short8 vl = *(const short8*)(num + (size_t)(4 + sp) * SZ_P + ybase + row * 64 + cg * 8);
#pragma unroll
            for (int j = 0; j < 8; ++j) {
                an[j] += bf2f((u16)vn[j]);
                al[j] += bf2f((u16)vl[j]);
            }
        }
        short8 ynl8, yl8;
#pragma unroll
        for (int j = 0; j < 8; ++j) {
            ynl8[j] = (short)f2bf(an[j] * inl);
            yl8[j]  = (short)f2bf(al[j] * ilo);
        }
        *(short8*)&ynl_s[row * 72 + cg * 8] = ynl8;
        *(short8*)&yl_s[row * 72 + cg * 8] = yl8;
    }
    __syncthreads();
    const float rsq = rsqrtf(1.0f + 1e-5f);
    const u16* wblW = wbf + 49152;
    const u16* wbW  = wbf + 53248;

    // E1: yy[n][io] = bn(relu(wWl . y_l)) + y_nl
    {
        const short8 a0 = *(const short8*)(wblW + (w * 16 + l15) * 64 + quad * 8);
        const short8 a1 = *(const short8*)(wblW + (w * 16 + l15) * 64 + 32 + quad * 8);
        float sc[4], bt[4];
#pragma unroll
        for (int r = 0; r < 4; ++r) {
            const int io = w * 16 + quad * 4 + r;
            sc[r] = gWl[io] * rsq;
            bt[r] = betaWl[io];
        }
        floatx4 acc = {0.f, 0.f, 0.f, 0.f};
        const u16* bp_ = &yl_s[l15 * 72 + quad * 8];
        acc = MFMA16(a0, *(const short8*)bp_, acc);
        acc = MFMA16(a1, *(const short8*)(bp_ + 32), acc);
#pragma unroll
        for (int r = 0; r < 4; ++r) {
            const int io = w * 16 + quad * 4 + r;
            float val = fmaxf(acc[r], 0.f) * sc[r] + bt[r];
            val += bf2f(ynl_s[l15 * 72 + io]);
            yy_s[l15 * 72 + io] = f2bf(val);
        }
    }
    __syncthreads();

    // E2: out[c][n] = bn(relu(wW . yy + bW)) + x
#pragma unroll
    for (int rb = 0; rb < 2; ++rb) {
        const int c0 = rb * 64 + w * 16;
        const short8 a0 = *(const short8*)(wbW + (c0 + l15) * 64 + quad * 8);
        const short8 a1 = *(const short8*)(wbW + (c0 + l15) * 64 + 32 + quad * 8);
        float bs[4], sc[4], bt[4];
#pragma unroll
        for (int r = 0; r < 4; ++r) {
            const int c = c0 + quad * 4 + r;
            bs[r] = bW[c];
            sc[r] = gW[c] * rsq;
            bt[r] = betaW[c];
        }
        floatx4 acc = {0.f, 0.f, 0.f, 0.f};
        const u16* bp_ = &yy_s[l15 * 72 + quad * 8];
        acc = MFMA16(a0, *(const short8*)bp_, acc);
        acc = MFMA16(a1, *(const short8*)(bp_ + 32), acc);
#pragma unroll
        for (int r = 0; r < 4; ++r) {
            const int c = c0 + quad * 4 + r;
            float val = fmaxf(acc[r] + bs[r], 0.f) * sc[r] + bt[r];
            const size_t xi = ((size_t)b << 19) + ((size_t)c << 12) + n0 + l15;
            out[xi] = val + x[xi];
        }
    }
}

// ---------------------------------------------------------------------------
extern "C" void kernel_launch(void* const* d_in, const int* in_sizes, int n_in,
                              void* d_out, int out_size, void* d_ws, size_t ws_size,
                              hipStream_t stream) {
    const float* x      = (const float*)d_in[0];
    const float* mask   = (const float*)d_in[1];
    const float* wt_nl  = (const float*)d_in[2];  const float* bt_nl = (const float*)d_in[3];
    const float* wp_nl  = (const float*)d_in[4];  const float* bp_nl = (const float*)d_in[5];
    const float* wt_l   = (const float*)d_in[6];  const float* bt_l  = (const float*)d_in[7];
    const float* wp_l   = (const float*)d_in[8];  const float* bp_l  = (const float*)d_in[9];
    const float* wg_nl  = (const float*)d_in[10]; const float* bg_nl = (const float*)d_in[11];
    const float* wg_l   = (const float*)d_in[12]; const float* bg_l  = (const float*)d_in[13];
    const float* wW     = (const float*)d_in[14]; const float* bW    = (const float*)d_in[15];
    const float* gW     = (const float*)d_in[16]; const float* betaW = (const float*)d_in[17];
    const float* wWl    = (const float*)d_in[18]; const float* gWl   = (const float*)d_in[19];
    const float* betaWl = (const float*)d_in[20];

    // ws: wbf 120KB + 6 qkv (12.6MB) + num 8x2MB (16.8MB) + den 512KB ~= 30 MB
    u16* ws  = (u16*)d_ws;
    u16* wbf = ws;                  // 61440
    u16* q0  = wbf + 61440;
    u16* k0  = q0 + SZ_P;
    u16* v0  = k0 + SZ_P;
    u16* q1  = v0 + SZ_P;
    u16* k1  = q1 + SZ_P;
    u16* v1  = k1 + SZ_P;
    u16* num = v1 + SZ_P;           // 8 x SZ_P (z = br*4+sp)
    float* den = (float*)(num + 8 * SZ_P);  // 8 x 16384 fp32

    k_prep_w<<<dim3(240), 256, 0, stream>>>(wt_nl, wp_nl, wg_nl,
                                            wt_l, wp_l, wg_l, wWl, wW, wbf);
    k_proj<<<dim3(64, 4, 4), 256, 0, stream>>>(x, mask, wbf,
        bt_nl, bp_nl, bg_nl, bt_l, bp_l, bg_l,
        q0, k0, v0, q1, k1, v1);
    k_flash<<<dim3(512), 512, 0, stream>>>(q0, k0, v0, q1, k1, v1, num, den);
    k_epi<<<dim3(256, 4), 256, 0, stream>>>(num, den, wbf, gWl, betaWl,
                                            bW, gW, betaW, x, (float*)d_out);
}